// Round 6
// baseline (2023.262 us; speedup 1.0000x reference)
//
#include <hip/hip_runtime.h>
#include <hip/hip_bf16.h>
#include <cfloat>

// Problem constants (match reference)
#define F_IN   128
#define H_DIM  128
#define D_TOT  385          // H*L + 1
#define KTOP   100
#define C1     16
#define C2     32
#define KW2    5
#define POOLW  (KTOP/2)             // 50
#define CONV2W (POOLW - KW2 + 1)    // 46
#define DENSE  (C2*CONV2W)          // 1472
#define MLPH   128
#define SORT_CAP 2048

// ---------------- histogram (int32 keys, clamped) ----------------
__global__ void hist_kernel(const int* __restrict__ keys, int n, int nbins, int* __restrict__ cnt) {
    int i = blockIdx.x * blockDim.x + threadIdx.x;
    if (i < n) {
        int k = keys[i];
        k = (k < 0) ? 0 : (k >= nbins ? nbins - 1 : k);
        atomicAdd(&cnt[k], 1);
    }
}

// ---------------- single-block exclusive scan ----------------
__global__ void scan_excl_kernel(const int* __restrict__ cnt, int n,
                                 int* __restrict__ start, int* __restrict__ cursor,
                                 float* __restrict__ dinv) {
    __shared__ int s[1024];
    __shared__ int carry_s;
    int tid = threadIdx.x;
    if (tid == 0) carry_s = 0;
    __syncthreads();
    for (int base = 0; base < n; base += 1024) {
        int i = base + tid;
        int v = (i < n) ? cnt[i] : 0;
        s[tid] = v;
        __syncthreads();
        for (int off = 1; off < 1024; off <<= 1) {
            int t = (tid >= off) ? s[tid - off] : 0;
            __syncthreads();
            s[tid] += t;
            __syncthreads();
        }
        int excl = s[tid] - v;
        int carry = carry_s;
        if (i < n) {
            start[i] = carry + excl;
            if (cursor) cursor[i] = carry + excl;
            if (dinv)   dinv[i]   = rsqrtf((float)v + 1.0f);
        }
        __syncthreads();
        if (tid == 0) carry_s += s[1023];
        __syncthreads();
    }
}

// ---------------- CSR fill (edges bucketed by dst, clamped) ----------------
__global__ void csr_fill_kernel(const int* __restrict__ src, const int* __restrict__ dst, int e, int n,
                                int* __restrict__ cursor, const float* __restrict__ dinv,
                                int* __restrict__ csr_src, float* __restrict__ csr_w) {
    int i = blockIdx.x * blockDim.x + threadIdx.x;
    if (i < e) {
        int s = src[i], d = dst[i];
        s = (s < 0) ? 0 : (s >= n ? n - 1 : s);
        d = (d < 0) ? 0 : (d >= n ? n - 1 : d);
        int pos = atomicAdd(&cursor[d], 1);
        csr_src[pos] = s;
        csr_w[pos]   = dinv[s] * dinv[d];
    }
}

// ---------------- fp32 GEMM: T[n,128] = A[n,:] (lda) @ W[128,128] ----------------
__global__ __launch_bounds__(256) void gemm_nk128(const float* __restrict__ A, int lda,
                                                  const float* __restrict__ W,
                                                  float* __restrict__ T, int n) {
    __shared__ float Al[64 * 128];   // XOR-swizzled along k
    __shared__ float Wl[128 * 64];
    int tid = threadIdx.x;
    int brow = blockIdx.x * 64;
    int chalf = blockIdx.y;          // 0/1 -> cols [0,64) or [64,128)

    for (int kk = tid >> 4; kk < 128; kk += 16) {
        int c4 = tid & 15;
        float4 w = *(const float4*)&W[kk * 128 + chalf * 64 + c4 * 4];
        *(float4*)&Wl[kk * 64 + c4 * 4] = w;
    }
    for (int idx = tid; idx < 64 * 128; idx += 256) {
        int rr = idx >> 7, k = idx & 127;
        int r = brow + rr;
        float a = (r < n) ? A[(size_t)r * lda + k] : 0.0f;
        Al[rr * 128 + (k ^ (rr & 31))] = a;
    }
    __syncthreads();

    int tr = tid >> 4, tc = tid & 15;
    int r0 = tr * 4;
    float acc[4][4] = {};
    #pragma unroll 4
    for (int k = 0; k < 128; k++) {
        float4 w = *(const float4*)&Wl[k * 64 + tc * 4];
        float a0 = Al[(r0 + 0) * 128 + (k ^ ((r0 + 0) & 31))];
        float a1 = Al[(r0 + 1) * 128 + (k ^ ((r0 + 1) & 31))];
        float a2 = Al[(r0 + 2) * 128 + (k ^ ((r0 + 2) & 31))];
        float a3 = Al[(r0 + 3) * 128 + (k ^ ((r0 + 3) & 31))];
        acc[0][0] += a0 * w.x; acc[0][1] += a0 * w.y; acc[0][2] += a0 * w.z; acc[0][3] += a0 * w.w;
        acc[1][0] += a1 * w.x; acc[1][1] += a1 * w.y; acc[1][2] += a1 * w.z; acc[1][3] += a1 * w.w;
        acc[2][0] += a2 * w.x; acc[2][1] += a2 * w.y; acc[2][2] += a2 * w.z; acc[2][3] += a2 * w.w;
        acc[3][0] += a3 * w.x; acc[3][1] += a3 * w.y; acc[3][2] += a3 * w.z; acc[3][3] += a3 * w.w;
    }
    for (int i = 0; i < 4; i++) {
        int r = brow + r0 + i;
        if (r < n) {
            float4 o = make_float4(acc[i][0], acc[i][1], acc[i][2], acc[i][3]);
            *(float4*)&T[(size_t)r * 128 + chalf * 64 + tc * 4] = o;
        }
    }
}

// ---------------- GCN aggregation (128-channel), pull-based ----------------
__global__ __launch_bounds__(128) void gcn_agg128(const float* __restrict__ T,
                                                  const int* __restrict__ csr_src,
                                                  const float* __restrict__ csr_w,
                                                  const int* __restrict__ row_start,
                                                  const int* __restrict__ cnt,
                                                  const float* __restrict__ dinv,
                                                  const float* __restrict__ bias,
                                                  float* __restrict__ feat, int layer, int n) {
    int i = blockIdx.x;
    int c = threadIdx.x;                 // 128 channels
    float di = dinv[i];
    float acc = T[(size_t)i * 128 + c] * di * di;   // self-loop
    int rs = row_start[i], ce = cnt[i];
    for (int e = 0; e < ce; e++) {
        int s  = csr_src[rs + e];
        float w = csr_w[rs + e];
        acc += T[(size_t)s * 128 + c] * w;
    }
    feat[(size_t)i * D_TOT + layer * 128 + c] = tanhf(acc + bias[c]);
}

// ---------------- layer 3: GEMV (128 -> 1) ----------------
__global__ void gemv_out1(const float* __restrict__ feat, const float* __restrict__ Wg3,
                          float* __restrict__ T3, int n) {
    int i = blockIdx.x * blockDim.x + threadIdx.x;
    if (i >= n) return;
    const float* row = feat + (size_t)i * D_TOT + 256;   // layer-2 output columns
    float acc = 0.f;
    #pragma unroll
    for (int k = 0; k < 128; k++) acc += row[k] * Wg3[k];
    T3[i] = acc;
}

// ---------------- layer 3 aggregation (1 channel) ----------------
__global__ void gcn_agg1(const float* __restrict__ T3,
                         const int* __restrict__ csr_src, const float* __restrict__ csr_w,
                         const int* __restrict__ row_start, const int* __restrict__ cnt,
                         const float* __restrict__ dinv, const float* __restrict__ bg3,
                         float* __restrict__ feat, int n) {
    int i = blockIdx.x * blockDim.x + threadIdx.x;
    if (i >= n) return;
    float di = dinv[i];
    float acc = T3[i] * di * di;
    int rs = row_start[i], ce = cnt[i];
    for (int e = 0; e < ce; e++) acc += T3[csr_src[rs + e]] * csr_w[rs + e];
    feat[(size_t)i * D_TOT + (D_TOT - 1)] = tanhf(acc + bg3[0]);
}

// ---------------- sort-pool: per-graph bitonic sort ----------------
// EXACT reference semantics: stable ascending argsort of fp32 key
//   key = 4.0f*(float)b - feat[:,-1]
// The fp32 rounding of (4b - v) at large b quantizes v onto a ~1e-4 grid,
// creating ties that the reference breaks by original index. We replicate
// that by sorting the fp32 key itself (ascending, idx ascending).
__global__ __launch_bounds__(256) void sortpool_kernel(const float* __restrict__ feat,
                                                       const int* __restrict__ gcnt,
                                                       const int* __restrict__ gstart,
                                                       int* __restrict__ sel) {
    int b = blockIdx.x, tid = threadIdx.x;
    __shared__ float sv[SORT_CAP];
    __shared__ int   si[SORT_CAP];
    int cnt = gcnt[b];
    if (cnt > SORT_CAP) cnt = SORT_CAP;
    int start = gstart[b];
    if (cnt == 0) {
        for (int j = tid; j < KTOP; j += 256) sel[b * KTOP + j] = -1;
        return;
    }
    float bb = 4.0f * (float)b;    // exact in fp32
    int P = 1; while (P < cnt) P <<= 1;
    for (int j = tid; j < P; j += 256) {
        if (j < cnt) {
            float v = feat[(size_t)(start + j) * D_TOT + (D_TOT - 1)];
            sv[j] = bb - v;        // single fp32 rounding, matches reference
            si[j] = j;
        } else { sv[j] = FLT_MAX; si[j] = j; }
    }
    __syncthreads();
    for (int ksz = 2; ksz <= P; ksz <<= 1) {
        for (int jj = ksz >> 1; jj > 0; jj >>= 1) {
            for (int t = tid; t < P; t += 256) {
                int l = t ^ jj;
                if (l > t) {
                    float va = sv[t], vb = sv[l];
                    int   ia = si[t], ib = si[l];
                    // ascending by (key, idx) — stable argsort semantics
                    bool aFirst = (va < vb) || (va == vb && ia < ib);
                    bool up = ((t & ksz) == 0);
                    if (up ? !aFirst : aFirst) {
                        sv[t] = vb; sv[l] = va; si[t] = ib; si[l] = ia;
                    }
                }
            }
            __syncthreads();
        }
    }
    for (int j = tid; j < KTOP; j += 256)
        sel[b * KTOP + j] = (j < cnt) ? (start + si[j]) : -1;
}

// ---------------- conv1: per (graph, position) 385-dot x 16 outputs ----------------
__global__ __launch_bounds__(128) void conv1_kernel(const float* __restrict__ feat,
                                                    const int* __restrict__ sel,
                                                    const float* __restrict__ W1,
                                                    const float* __restrict__ b1,
                                                    float* __restrict__ h1) {
    int blk = blockIdx.x;             // b*KTOP + j
    int b = blk / KTOP, j = blk % KTOP;
    int tid = threadIdx.x;
    int o = tid & 15, seg = tid >> 4; // 16 outputs x 8 segments
    int row = sel[blk];
    float partial = 0.f;
    if (row >= 0) {
        const float* fr = feat + (size_t)row * D_TOT;
        for (int t = seg; t < D_TOT; t += 8)
            partial += fr[t] * W1[o * D_TOT + t];
    }
    __shared__ float red[128];
    red[tid] = partial;
    __syncthreads();
    if (tid < 16) {
        float s = 0.f;
        #pragma unroll
        for (int g = 0; g < 8; g++) s += red[g * 16 + tid];
        h1[((size_t)b * C1 + tid) * KTOP + j] = fmaxf(s + b1[tid], 0.f);
    }
}

// ---------------- head: maxpool + conv2 + MLP, one block per graph ----------------
__global__ __launch_bounds__(256) void head_kernel(const float* __restrict__ h1,
                                                   const float* __restrict__ W2, const float* __restrict__ b2,
                                                   const float* __restrict__ Wm1, const float* __restrict__ bm1,
                                                   const float* __restrict__ Wm2, const float* __restrict__ bm2,
                                                   float* __restrict__ out) {
    int b = blockIdx.x, tid = threadIdx.x;
    __shared__ float pool[C1 * POOLW];   // 800
    __shared__ float flat[DENSE];        // 1472
    __shared__ float hid[MLPH];          // 128
    __shared__ float red[256];

    for (int p = tid; p < C1 * POOLW; p += 256) {
        int i = p / POOLW, t = p % POOLW;
        float v0 = h1[((size_t)b * C1 + i) * KTOP + 2 * t];
        float v1 = h1[((size_t)b * C1 + i) * KTOP + 2 * t + 1];
        pool[i * POOLW + t] = fmaxf(v0, v1);
    }
    __syncthreads();
    for (int q = tid; q < DENSE; q += 256) {
        int o = q / CONV2W, t = q % CONV2W;
        float acc = b2[o];
        #pragma unroll
        for (int i = 0; i < C1; i++) {
            #pragma unroll
            for (int ks = 0; ks < KW2; ks++)
                acc += pool[i * POOLW + t + ks] * W2[(o * C1 + i) * KW2 + ks];
        }
        flat[o * CONV2W + t] = fmaxf(acc, 0.f);
    }
    __syncthreads();
    {
        int h = tid & 127, part = tid >> 7;     // 2 partials per output
        float acc = 0.f;
        for (int t = part * (DENSE / 2); t < (part + 1) * (DENSE / 2); t++)
            acc += flat[t] * Wm1[(size_t)t * MLPH + h];
        red[tid] = acc;
    }
    __syncthreads();
    if (tid < 128) hid[tid] = fmaxf(red[tid] + red[tid + 128] + bm1[tid], 0.f);
    __syncthreads();
    if (tid < 64) {
        float p = hid[tid] * Wm2[tid] + hid[tid + 64] * Wm2[tid + 64];
        #pragma unroll
        for (int off = 32; off > 0; off >>= 1) p += __shfl_down(p, off, 64);
        if (tid == 0) out[b] = p + bm2[0];
    }
}

// ================= launch =================
extern "C" void kernel_launch(void* const* d_in, const int* in_sizes, int n_in,
                              void* d_out, int out_size, void* d_ws, size_t ws_size,
                              hipStream_t stream) {
    const float* x     = (const float*)d_in[0];
    const int*   ei    = (const int*)d_in[1];
    const int*   batch = (const int*)d_in[2];
    const float* Wg0 = (const float*)d_in[4],  *bg0 = (const float*)d_in[5];
    const float* Wg1 = (const float*)d_in[6],  *bg1 = (const float*)d_in[7];
    const float* Wg2 = (const float*)d_in[8],  *bg2 = (const float*)d_in[9];
    const float* Wg3 = (const float*)d_in[10], *bg3 = (const float*)d_in[11];
    const float* W1  = (const float*)d_in[12], *b1  = (const float*)d_in[13];
    const float* W2  = (const float*)d_in[14], *b2  = (const float*)d_in[15];
    const float* Wm1 = (const float*)d_in[16], *bm1 = (const float*)d_in[17];
    const float* Wm2 = (const float*)d_in[18], *bm2 = (const float*)d_in[19];
    float* out = (float*)d_out;

    const int N = in_sizes[2];        // batch has N elements
    const int E = in_sizes[1] / 2;
    const int B = out_size;           // 512
    const int* src = ei;
    const int* dst = ei + E;

    // ---- workspace budget check (prevent OOB scribble -> container death) ----
    auto rup = [](size_t b) { return (b + 255) & ~(size_t)255; };
    size_t need = 0;
    need += rup((size_t)N * 4) * 4;                 // cnt_node,row_start,cursor,dinv
    need += rup((size_t)B * 4) * 2;                 // gcnt,gstart
    need += rup((size_t)E * 4) * 2;                 // csr_src,csr_w
    need += rup((size_t)N * 128 * 4);               // T
    need += rup((size_t)N * D_TOT * 4);             // feat
    need += rup((size_t)B * KTOP * 4);              // sel
    need += rup((size_t)B * C1 * KTOP * 4);         // h1
    if (need > ws_size) {
        hipMemsetAsync(d_out, 0, (size_t)out_size * 4, stream);
        return;
    }

    // workspace carve
    char* p = (char*)d_ws;
    auto alloc = [&](size_t bytes) { void* r = (void*)p; p += (bytes + 255) & ~(size_t)255; return r; };
    int*   cnt_node  = (int*)alloc((size_t)N * 4);
    int*   row_start = (int*)alloc((size_t)N * 4);
    int*   cursor    = (int*)alloc((size_t)N * 4);
    float* dinv      = (float*)alloc((size_t)N * 4);
    int*   gcnt      = (int*)alloc((size_t)B * 4);
    int*   gstart    = (int*)alloc((size_t)B * 4);
    int*   csr_src   = (int*)alloc((size_t)E * 4);
    float* csr_w     = (float*)alloc((size_t)E * 4);
    float* T         = (float*)alloc((size_t)N * 128 * 4);
    float* feat      = (float*)alloc((size_t)N * D_TOT * 4);
    int*   sel       = (int*)alloc((size_t)B * KTOP * 4);
    float* h1        = (float*)alloc((size_t)B * C1 * KTOP * 4);

    hipMemsetAsync(cnt_node, 0, (size_t)N * 4, stream);
    hipMemsetAsync(gcnt,     0, (size_t)B * 4, stream);

    hist_kernel<<<(E + 255) / 256, 256, 0, stream>>>(dst, E, N, cnt_node);
    hist_kernel<<<(N + 255) / 256, 256, 0, stream>>>(batch, N, B, gcnt);

    scan_excl_kernel<<<1, 1024, 0, stream>>>(cnt_node, N, row_start, cursor, dinv);
    scan_excl_kernel<<<1, 1024, 0, stream>>>(gcnt, B, gstart, nullptr, nullptr);

    csr_fill_kernel<<<(E + 255) / 256, 256, 0, stream>>>(src, dst, E, N, cursor, dinv, csr_src, csr_w);

    dim3 ggrid((N + 63) / 64, 2);
    // layer 0: x(F=128) -> feat cols [0,128)
    gemm_nk128<<<ggrid, 256, 0, stream>>>(x, F_IN, Wg0, T, N);
    gcn_agg128<<<N, 128, 0, stream>>>(T, csr_src, csr_w, row_start, cnt_node, dinv, bg0, feat, 0, N);
    // layer 1: feat cols [0,128) -> [128,256)
    gemm_nk128<<<ggrid, 256, 0, stream>>>(feat, D_TOT, Wg1, T, N);
    gcn_agg128<<<N, 128, 0, stream>>>(T, csr_src, csr_w, row_start, cnt_node, dinv, bg1, feat, 1, N);
    // layer 2: feat cols [128,256) -> [256,384)
    gemm_nk128<<<ggrid, 256, 0, stream>>>(feat + 128, D_TOT, Wg2, T, N);
    gcn_agg128<<<N, 128, 0, stream>>>(T, csr_src, csr_w, row_start, cnt_node, dinv, bg2, feat, 2, N);
    // layer 3: feat cols [256,384) -> col 384 (1 channel)
    gemv_out1<<<(N + 255) / 256, 256, 0, stream>>>(feat, Wg3, T, N);
    gcn_agg1<<<(N + 255) / 256, 256, 0, stream>>>(T, csr_src, csr_w, row_start, cnt_node, dinv, bg3, feat, N);

    sortpool_kernel<<<B, 256, 0, stream>>>(feat, gcnt, gstart, sel);
    conv1_kernel<<<B * KTOP, 128, 0, stream>>>(feat, sel, W1, b1, h1);
    head_kernel<<<B, 256, 0, stream>>>(h1, W2, b2, Wm1, bm1, Wm2, bm2, out);
}

// Round 8
// 1583.538 us; speedup vs baseline: 1.2777x; 1.2777x over previous
//
#include <hip/hip_runtime.h>
#include <hip/hip_bf16.h>
#include <cfloat>

// Problem constants (match reference)
#define F_IN   128
#define H_DIM  128
#define D_TOT  385          // H*L + 1
#define KTOP   100
#define C1     16
#define C2     32
#define KW2    5
#define POOLW  (KTOP/2)             // 50
#define CONV2W (POOLW - KW2 + 1)    // 46
#define DENSE  (C2*CONV2W)          // 1472
#define MLPH   128
#define SORT_CAP 2048
#define D_PAD  388                  // 385 padded to /4 for float4 LDS reads
#define C1SLOTS 32                  // rows per conv1 block
#define SCHUNK 1024                 // scan chunk

// ---------------- histogram (int32 keys, clamped) ----------------
__global__ void hist_kernel(const int* __restrict__ keys, int n, int nbins, int* __restrict__ cnt) {
    int i = blockIdx.x * blockDim.x + threadIdx.x;
    if (i < n) {
        int k = keys[i];
        k = (k < 0) ? 0 : (k >= nbins ? nbins - 1 : k);
        atomicAdd(&cnt[k], 1);
    }
}

// ---------------- single-block exclusive scan (small n / chunk sums) ----------------
__global__ void scan_excl_kernel(const int* __restrict__ cnt, int n,
                                 int* __restrict__ start, int* __restrict__ cursor,
                                 float* __restrict__ dinv) {
    __shared__ int s[1024];
    __shared__ int carry_s;
    int tid = threadIdx.x;
    if (tid == 0) carry_s = 0;
    __syncthreads();
    for (int base = 0; base < n; base += 1024) {
        int i = base + tid;
        int v = (i < n) ? cnt[i] : 0;
        s[tid] = v;
        __syncthreads();
        for (int off = 1; off < 1024; off <<= 1) {
            int t = (tid >= off) ? s[tid - off] : 0;
            __syncthreads();
            s[tid] += t;
            __syncthreads();
        }
        int excl = s[tid] - v;
        int carry = carry_s;
        if (i < n) {
            start[i] = carry + excl;
            if (cursor) cursor[i] = carry + excl;
            if (dinv)   dinv[i]   = rsqrtf((float)v + 1.0f);
        }
        __syncthreads();
        if (tid == 0) carry_s += s[1023];
        __syncthreads();
    }
}

// ---------------- hierarchical scan, phase 1: per-chunk sums ----------------
__global__ __launch_bounds__(256) void chunksum_kernel(const int* __restrict__ cnt, int n,
                                                       int* __restrict__ bsum) {
    __shared__ int red[256];
    int blk = blockIdx.x, tid = threadIdx.x;
    int base = blk * SCHUNK;
    int s = 0;
    for (int idx = tid; idx < SCHUNK; idx += 256) {
        int i = base + idx;
        s += (i < n) ? cnt[i] : 0;
    }
    red[tid] = s; __syncthreads();
    for (int off = 128; off > 0; off >>= 1) {
        if (tid < off) red[tid] += red[tid + off];
        __syncthreads();
    }
    if (tid == 0) bsum[blk] = red[0];
}

// ---------------- hierarchical scan, phase 3: apply ----------------
__global__ __launch_bounds__(256) void scan_apply_kernel(const int* __restrict__ cnt, int n,
                                                         const int* __restrict__ bstart,
                                                         int* __restrict__ start,
                                                         int* __restrict__ cursor,
                                                         float* __restrict__ dinv) {
    __shared__ int tsum[256];
    int blk = blockIdx.x, tid = threadIdx.x;
    int base = blk * SCHUNK + tid * 4;
    int v[4];
    #pragma unroll
    for (int k = 0; k < 4; k++) { int i = base + k; v[k] = (i < n) ? cnt[i] : 0; }
    int loc = v[0] + v[1] + v[2] + v[3];
    tsum[tid] = loc; __syncthreads();
    int x = loc;
    for (int off = 1; off < 256; off <<= 1) {
        int t = (tid >= off) ? tsum[tid - off] : 0;
        __syncthreads();
        x += t; tsum[tid] = x;
        __syncthreads();
    }
    int run = x - loc + bstart[blk];
    #pragma unroll
    for (int k = 0; k < 4; k++) {
        int i = base + k;
        if (i < n) {
            start[i]  = run;
            cursor[i] = run;
            dinv[i]   = rsqrtf((float)v[k] + 1.0f);
        }
        run += v[k];
    }
}

// ---------------- CSR fill (edges bucketed by dst, clamped) ----------------
__global__ void csr_fill_kernel(const int* __restrict__ src, const int* __restrict__ dst, int e, int n,
                                int* __restrict__ cursor, const float* __restrict__ dinv,
                                int* __restrict__ csr_src, float* __restrict__ csr_w) {
    int i = blockIdx.x * blockDim.x + threadIdx.x;
    if (i < e) {
        int s = src[i], d = dst[i];
        s = (s < 0) ? 0 : (s >= n ? n - 1 : s);
        d = (d < 0) ? 0 : (d >= n ? n - 1 : d);
        int pos = atomicAdd(&cursor[d], 1);
        csr_src[pos] = s;
        csr_w[pos]   = dinv[s] * dinv[d];
    }
}

// ---------------- fp32 GEMM: T[n,128] = A[n,:] (lda) @ W[128,128] ----------------
__global__ __launch_bounds__(256) void gemm_nk128(const float* __restrict__ A, int lda,
                                                  const float* __restrict__ W,
                                                  float* __restrict__ T, int n) {
    __shared__ float Al[64 * 128];   // XOR-swizzled along k
    __shared__ float Wl[128 * 64];
    int tid = threadIdx.x;
    int brow = blockIdx.x * 64;
    int chalf = blockIdx.y;          // 0/1 -> cols [0,64) or [64,128)

    for (int kk = tid >> 4; kk < 128; kk += 16) {
        int c4 = tid & 15;
        float4 w = *(const float4*)&W[kk * 128 + chalf * 64 + c4 * 4];
        *(float4*)&Wl[kk * 64 + c4 * 4] = w;
    }
    for (int idx = tid; idx < 64 * 128; idx += 256) {
        int rr = idx >> 7, k = idx & 127;
        int r = brow + rr;
        float a = (r < n) ? A[(size_t)r * lda + k] : 0.0f;
        Al[rr * 128 + (k ^ (rr & 31))] = a;
    }
    __syncthreads();

    int tr = tid >> 4, tc = tid & 15;
    int r0 = tr * 4;
    float acc[4][4] = {};
    #pragma unroll 4
    for (int k = 0; k < 128; k++) {
        float4 w = *(const float4*)&Wl[k * 64 + tc * 4];
        float a0 = Al[(r0 + 0) * 128 + (k ^ ((r0 + 0) & 31))];
        float a1 = Al[(r0 + 1) * 128 + (k ^ ((r0 + 1) & 31))];
        float a2 = Al[(r0 + 2) * 128 + (k ^ ((r0 + 2) & 31))];
        float a3 = Al[(r0 + 3) * 128 + (k ^ ((r0 + 3) & 31))];
        acc[0][0] += a0 * w.x; acc[0][1] += a0 * w.y; acc[0][2] += a0 * w.z; acc[0][3] += a0 * w.w;
        acc[1][0] += a1 * w.x; acc[1][1] += a1 * w.y; acc[1][2] += a1 * w.z; acc[1][3] += a1 * w.w;
        acc[2][0] += a2 * w.x; acc[2][1] += a2 * w.y; acc[2][2] += a2 * w.z; acc[2][3] += a2 * w.w;
        acc[3][0] += a3 * w.x; acc[3][1] += a3 * w.y; acc[3][2] += a3 * w.z; acc[3][3] += a3 * w.w;
    }
    for (int i = 0; i < 4; i++) {
        int r = brow + r0 + i;
        if (r < n) {
            float4 o = make_float4(acc[i][0], acc[i][1], acc[i][2], acc[i][3]);
            *(float4*)&T[(size_t)r * 128 + chalf * 64 + tc * 4] = o;
        }
    }
}

// ---------------- GCN aggregation (128-channel), pull-based ----------------
// Optionally fuses the layer-3 GEMV (128->1, weights Wg3) into the epilogue,
// writing T3[i] — saves a full 51 MB uncoalesced re-read of feat.
__global__ __launch_bounds__(128) void gcn_agg128(const float* __restrict__ T,
                                                  const int* __restrict__ csr_src,
                                                  const float* __restrict__ csr_w,
                                                  const int* __restrict__ row_start,
                                                  const int* __restrict__ cnt,
                                                  const float* __restrict__ dinv,
                                                  const float* __restrict__ bias,
                                                  float* __restrict__ feat, int layer, int n,
                                                  const float* __restrict__ Wg3,
                                                  float* __restrict__ T3) {
    int i = blockIdx.x;
    int c = threadIdx.x;                 // 128 channels
    float di = dinv[i];
    float acc = T[(size_t)i * 128 + c] * di * di;   // self-loop
    int rs = row_start[i], ce = cnt[i];
    for (int e = 0; e < ce; e++) {
        int s  = csr_src[rs + e];
        float w = csr_w[rs + e];
        acc += T[(size_t)s * 128 + c] * w;
    }
    float v = tanhf(acc + bias[c]);
    feat[(size_t)i * D_TOT + layer * 128 + c] = v;
    if (T3 != nullptr) {                 // uniform branch
        __shared__ float red[128];
        red[c] = v * Wg3[c];
        __syncthreads();
        for (int off = 64; off > 0; off >>= 1) {
            if (c < off) red[c] += red[c + off];
            __syncthreads();
        }
        if (c == 0) T3[i] = red[0];
    }
}

// ---------------- layer 3 aggregation (1 channel) ----------------
__global__ void gcn_agg1(const float* __restrict__ T3,
                         const int* __restrict__ csr_src, const float* __restrict__ csr_w,
                         const int* __restrict__ row_start, const int* __restrict__ cnt,
                         const float* __restrict__ dinv, const float* __restrict__ bg3,
                         float* __restrict__ feat, int n) {
    int i = blockIdx.x * blockDim.x + threadIdx.x;
    if (i >= n) return;
    float di = dinv[i];
    float acc = T3[i] * di * di;
    int rs = row_start[i], ce = cnt[i];
    for (int e = 0; e < ce; e++) acc += T3[csr_src[rs + e]] * csr_w[rs + e];
    feat[(size_t)i * D_TOT + (D_TOT - 1)] = tanhf(acc + bg3[0]);
}

// ---------------- sort-pool: per-graph bitonic sort ----------------
// EXACT reference semantics: stable ascending argsort of fp32 key
//   key = 4.0f*(float)b - feat[:,-1]
__global__ __launch_bounds__(256) void sortpool_kernel(const float* __restrict__ feat,
                                                       const int* __restrict__ gcnt,
                                                       const int* __restrict__ gstart,
                                                       int* __restrict__ sel) {
    int b = blockIdx.x, tid = threadIdx.x;
    __shared__ float sv[SORT_CAP];
    __shared__ int   si[SORT_CAP];
    int cnt = gcnt[b];
    if (cnt > SORT_CAP) cnt = SORT_CAP;
    int start = gstart[b];
    if (cnt == 0) {
        for (int j = tid; j < KTOP; j += 256) sel[b * KTOP + j] = -1;
        return;
    }
    float bb = 4.0f * (float)b;    // exact in fp32
    int P = 1; while (P < cnt) P <<= 1;
    for (int j = tid; j < P; j += 256) {
        if (j < cnt) {
            float v = feat[(size_t)(start + j) * D_TOT + (D_TOT - 1)];
            sv[j] = bb - v;        // single fp32 rounding, matches reference
            si[j] = j;
        } else { sv[j] = FLT_MAX; si[j] = j; }
    }
    __syncthreads();
    for (int ksz = 2; ksz <= P; ksz <<= 1) {
        for (int jj = ksz >> 1; jj > 0; jj >>= 1) {
            for (int t = tid; t < P; t += 256) {
                int l = t ^ jj;
                if (l > t) {
                    float va = sv[t], vb = sv[l];
                    int   ia = si[t], ib = si[l];
                    bool aFirst = (va < vb) || (va == vb && ia < ib);
                    bool up = ((t & ksz) == 0);
                    if (up ? !aFirst : aFirst) {
                        sv[t] = vb; sv[l] = va; si[t] = ib; si[l] = ia;
                    }
                }
            }
            __syncthreads();
        }
    }
    for (int j = tid; j < KTOP; j += 256)
        sel[b * KTOP + j] = (j < cnt) ? (start + si[j]) : -1;
}

// ---------------- conv1 (rewritten): LDS-staged, coalesced, float4 ----------------
// Each block: 32 slots x 16 outputs. Stage W1 (16x385, padded 388) and 32 feat
// rows in LDS with coalesced loads; each thread computes 2 rows x 1 output via
// float4 LDS reads (broadcast-friendly banks). Replaces the transaction-bound
// version that ran at 427 us (VALUBusy 10%, HBM 1.3%).
__global__ __launch_bounds__(256) void conv1_kernel(const float* __restrict__ feat,
                                                    const int* __restrict__ sel,
                                                    const float* __restrict__ W1,
                                                    const float* __restrict__ b1,
                                                    float* __restrict__ h1, int nslots) {
    __shared__ float W1l[C1 * D_PAD];        // 24832 B
    __shared__ float rows[C1SLOTS * D_PAD];  // 49664 B
    int tid = threadIdx.x;
    int base = blockIdx.x * C1SLOTS;

    for (int idx = tid; idx < C1 * D_TOT; idx += 256) {
        int o = idx / D_TOT, t = idx - o * D_TOT;
        W1l[o * D_PAD + t] = W1[idx];
    }
    for (int idx = tid; idx < C1SLOTS * D_TOT; idx += 256) {
        int r = idx / D_TOT, t = idx - r * D_TOT;
        int slot = base + r;
        float v = 0.f;
        if (slot < nslots) {
            int row = sel[slot];
            if (row >= 0) v = feat[(size_t)row * D_TOT + t];
        }
        rows[r * D_PAD + t] = v;
    }
    __syncthreads();

    int g = tid >> 4, o = tid & 15;   // g: 0..15 -> rows 2g, 2g+1
    int r0 = 2 * g;
    const float* wr = &W1l[o * D_PAD];
    const float* p0 = &rows[r0 * D_PAD];
    const float* p1 = &rows[(r0 + 1) * D_PAD];
    float a0 = 0.f, a1 = 0.f;
    #pragma unroll 4
    for (int t = 0; t < 384; t += 4) {
        float4 w  = *(const float4*)&wr[t];
        float4 x0 = *(const float4*)&p0[t];
        float4 x1 = *(const float4*)&p1[t];
        a0 += x0.x * w.x + x0.y * w.y + x0.z * w.z + x0.w * w.w;
        a1 += x1.x * w.x + x1.y * w.y + x1.z * w.z + x1.w * w.w;
    }
    a0 += p0[384] * wr[384];
    a1 += p1[384] * wr[384];

    float bo = b1[o];
    int slot0 = base + r0;
    if (slot0 < nslots) {
        int b = slot0 / KTOP, j = slot0 - b * KTOP;
        h1[((size_t)b * C1 + o) * KTOP + j] = fmaxf(a0 + bo, 0.f);
    }
    int slot1 = slot0 + 1;
    if (slot1 < nslots) {
        int b = slot1 / KTOP, j = slot1 - b * KTOP;
        h1[((size_t)b * C1 + o) * KTOP + j] = fmaxf(a1 + bo, 0.f);
    }
}

// ---------------- head: maxpool + conv2 + MLP, one block per graph ----------------
__global__ __launch_bounds__(256) void head_kernel(const float* __restrict__ h1,
                                                   const float* __restrict__ W2, const float* __restrict__ b2,
                                                   const float* __restrict__ Wm1, const float* __restrict__ bm1,
                                                   const float* __restrict__ Wm2, const float* __restrict__ bm2,
                                                   float* __restrict__ out) {
    int b = blockIdx.x, tid = threadIdx.x;
    __shared__ float pool[C1 * POOLW];   // 800
    __shared__ float flat[DENSE];        // 1472
    __shared__ float hid[MLPH];          // 128
    __shared__ float red[256];

    for (int p = tid; p < C1 * POOLW; p += 256) {
        int i = p / POOLW, t = p % POOLW;
        float v0 = h1[((size_t)b * C1 + i) * KTOP + 2 * t];
        float v1 = h1[((size_t)b * C1 + i) * KTOP + 2 * t + 1];
        pool[i * POOLW + t] = fmaxf(v0, v1);
    }
    __syncthreads();
    for (int q = tid; q < DENSE; q += 256) {
        int o = q / CONV2W, t = q % CONV2W;
        float acc = b2[o];
        #pragma unroll
        for (int i = 0; i < C1; i++) {
            #pragma unroll
            for (int ks = 0; ks < KW2; ks++)
                acc += pool[i * POOLW + t + ks] * W2[(o * C1 + i) * KW2 + ks];
        }
        flat[o * CONV2W + t] = fmaxf(acc, 0.f);
    }
    __syncthreads();
    {
        int h = tid & 127, part = tid >> 7;     // 2 partials per output
        float acc = 0.f;
        for (int t = part * (DENSE / 2); t < (part + 1) * (DENSE / 2); t++)
            acc += flat[t] * Wm1[(size_t)t * MLPH + h];
        red[tid] = acc;
    }
    __syncthreads();
    if (tid < 128) hid[tid] = fmaxf(red[tid] + red[tid + 128] + bm1[tid], 0.f);
    __syncthreads();
    if (tid < 64) {
        float p = hid[tid] * Wm2[tid] + hid[tid + 64] * Wm2[tid + 64];
        #pragma unroll
        for (int off = 32; off > 0; off >>= 1) p += __shfl_down(p, off, 64);
        if (tid == 0) out[b] = p + bm2[0];
    }
}

// ================= launch =================
extern "C" void kernel_launch(void* const* d_in, const int* in_sizes, int n_in,
                              void* d_out, int out_size, void* d_ws, size_t ws_size,
                              hipStream_t stream) {
    const float* x     = (const float*)d_in[0];
    const int*   ei    = (const int*)d_in[1];
    const int*   batch = (const int*)d_in[2];
    const float* Wg0 = (const float*)d_in[4],  *bg0 = (const float*)d_in[5];
    const float* Wg1 = (const float*)d_in[6],  *bg1 = (const float*)d_in[7];
    const float* Wg2 = (const float*)d_in[8],  *bg2 = (const float*)d_in[9];
    const float* Wg3 = (const float*)d_in[10], *bg3 = (const float*)d_in[11];
    const float* W1  = (const float*)d_in[12], *b1  = (const float*)d_in[13];
    const float* W2  = (const float*)d_in[14], *b2  = (const float*)d_in[15];
    const float* Wm1 = (const float*)d_in[16], *bm1 = (const float*)d_in[17];
    const float* Wm2 = (const float*)d_in[18], *bm2 = (const float*)d_in[19];
    float* out = (float*)d_out;

    const int N = in_sizes[2];        // batch has N elements
    const int E = in_sizes[1] / 2;
    const int B = out_size;           // 512
    const int* src = ei;
    const int* dst = ei + E;
    const int nb = (N + SCHUNK - 1) / SCHUNK;

    // ---- workspace budget check ----
    auto rup = [](size_t b) { return (b + 255) & ~(size_t)255; };
    size_t need = 0;
    need += rup((size_t)N * 4) * 4;                 // cnt_node,row_start,cursor,dinv
    need += rup((size_t)N * 4);                     // T3
    need += rup((size_t)nb * 4) * 2;                // bsum,bstart
    need += rup((size_t)B * 4) * 2;                 // gcnt,gstart
    need += rup((size_t)E * 4) * 2;                 // csr_src,csr_w
    need += rup((size_t)N * 128 * 4);               // T
    need += rup((size_t)N * D_TOT * 4);             // feat
    need += rup((size_t)B * KTOP * 4);              // sel
    need += rup((size_t)B * C1 * KTOP * 4);         // h1
    if (need > ws_size) {
        hipMemsetAsync(d_out, 0, (size_t)out_size * 4, stream);
        return;
    }

    // workspace carve
    char* p = (char*)d_ws;
    auto alloc = [&](size_t bytes) { void* r = (void*)p; p += (bytes + 255) & ~(size_t)255; return r; };
    int*   cnt_node  = (int*)alloc((size_t)N * 4);
    int*   row_start = (int*)alloc((size_t)N * 4);
    int*   cursor    = (int*)alloc((size_t)N * 4);
    float* dinv      = (float*)alloc((size_t)N * 4);
    float* T3        = (float*)alloc((size_t)N * 4);
    int*   bsum      = (int*)alloc((size_t)nb * 4);
    int*   bstart    = (int*)alloc((size_t)nb * 4);
    int*   gcnt      = (int*)alloc((size_t)B * 4);
    int*   gstart    = (int*)alloc((size_t)B * 4);
    int*   csr_src   = (int*)alloc((size_t)E * 4);
    float* csr_w     = (float*)alloc((size_t)E * 4);
    float* T         = (float*)alloc((size_t)N * 128 * 4);
    float* feat      = (float*)alloc((size_t)N * D_TOT * 4);
    int*   sel       = (int*)alloc((size_t)B * KTOP * 4);
    float* h1        = (float*)alloc((size_t)B * C1 * KTOP * 4);

    hipMemsetAsync(cnt_node, 0, (size_t)N * 4, stream);
    hipMemsetAsync(gcnt,     0, (size_t)B * 4, stream);

    hist_kernel<<<(E + 255) / 256, 256, 0, stream>>>(dst, E, N, cnt_node);
    hist_kernel<<<(N + 255) / 256, 256, 0, stream>>>(batch, N, B, gcnt);

    // hierarchical exclusive scan over node degrees (parallel; replaces 98-chunk serial scan)
    chunksum_kernel<<<nb, 256, 0, stream>>>(cnt_node, N, bsum);
    scan_excl_kernel<<<1, 1024, 0, stream>>>(bsum, nb, bstart, nullptr, nullptr);
    scan_apply_kernel<<<nb, 256, 0, stream>>>(cnt_node, N, bstart, row_start, cursor, dinv);
    // per-graph counts: B=512 -> single chunk, keep simple scan
    scan_excl_kernel<<<1, 1024, 0, stream>>>(gcnt, B, gstart, nullptr, nullptr);

    csr_fill_kernel<<<(E + 255) / 256, 256, 0, stream>>>(src, dst, E, N, cursor, dinv, csr_src, csr_w);

    dim3 ggrid((N + 63) / 64, 2);
    // layer 0: x(F=128) -> feat cols [0,128)
    gemm_nk128<<<ggrid, 256, 0, stream>>>(x, F_IN, Wg0, T, N);
    gcn_agg128<<<N, 128, 0, stream>>>(T, csr_src, csr_w, row_start, cnt_node, dinv, bg0, feat, 0, N, nullptr, nullptr);
    // layer 1: feat cols [0,128) -> [128,256)
    gemm_nk128<<<ggrid, 256, 0, stream>>>(feat, D_TOT, Wg1, T, N);
    gcn_agg128<<<N, 128, 0, stream>>>(T, csr_src, csr_w, row_start, cnt_node, dinv, bg1, feat, 1, N, nullptr, nullptr);
    // layer 2: feat cols [128,256) -> [256,384), fused with layer-3 GEMV -> T3
    gemm_nk128<<<ggrid, 256, 0, stream>>>(feat + 128, D_TOT, Wg2, T, N);
    gcn_agg128<<<N, 128, 0, stream>>>(T, csr_src, csr_w, row_start, cnt_node, dinv, bg2, feat, 2, N, Wg3, T3);
    // layer 3 aggregation (1 channel)
    gcn_agg1<<<(N + 255) / 256, 256, 0, stream>>>(T3, csr_src, csr_w, row_start, cnt_node, dinv, bg3, feat, N);

    sortpool_kernel<<<B, 256, 0, stream>>>(feat, gcnt, gstart, sel);
    conv1_kernel<<<(B * KTOP + C1SLOTS - 1) / C1SLOTS, 256, 0, stream>>>(feat, sel, W1, b1, h1, B * KTOP);
    head_kernel<<<B, 256, 0, stream>>>(h1, W2, b2, Wm1, bm1, Wm2, bm2, out);
}

// Round 9
// 1397.133 us; speedup vs baseline: 1.4482x; 1.1334x over previous
//
#include <hip/hip_runtime.h>
#include <hip/hip_bf16.h>
#include <cfloat>

// Problem constants (match reference)
#define F_IN   128
#define H_DIM  128
#define D_TOT  385          // H*L + 1
#define KTOP   100
#define C1     16
#define C2     32
#define KW2    5
#define POOLW  (KTOP/2)             // 50
#define CONV2W (POOLW - KW2 + 1)    // 46
#define DENSE  (C2*CONV2W)          // 1472
#define MLPH   128
#define SORT_CAP 2048
#define D_PAD  388                  // 385 padded to /4 for float4 LDS reads
#define C1SLOTS 32                  // rows per conv1 block
#define SCHUNK 1024                 // scan chunk
#define AGG_NPB 8                   // nodes per aggregation block

// ---------------- histogram (int32 keys, clamped) ----------------
__global__ void hist_kernel(const int* __restrict__ keys, int n, int nbins, int* __restrict__ cnt) {
    int i = blockIdx.x * blockDim.x + threadIdx.x;
    if (i < n) {
        int k = keys[i];
        k = (k < 0) ? 0 : (k >= nbins ? nbins - 1 : k);
        atomicAdd(&cnt[k], 1);
    }
}

// ---------------- single-block exclusive scan (small n / chunk sums) ----------------
__global__ void scan_excl_kernel(const int* __restrict__ cnt, int n,
                                 int* __restrict__ start, int* __restrict__ cursor,
                                 float* __restrict__ dinv) {
    __shared__ int s[1024];
    __shared__ int carry_s;
    int tid = threadIdx.x;
    if (tid == 0) carry_s = 0;
    __syncthreads();
    for (int base = 0; base < n; base += 1024) {
        int i = base + tid;
        int v = (i < n) ? cnt[i] : 0;
        s[tid] = v;
        __syncthreads();
        for (int off = 1; off < 1024; off <<= 1) {
            int t = (tid >= off) ? s[tid - off] : 0;
            __syncthreads();
            s[tid] += t;
            __syncthreads();
        }
        int excl = s[tid] - v;
        int carry = carry_s;
        if (i < n) {
            start[i] = carry + excl;
            if (cursor) cursor[i] = carry + excl;
            if (dinv)   dinv[i]   = rsqrtf((float)v + 1.0f);
        }
        __syncthreads();
        if (tid == 0) carry_s += s[1023];
        __syncthreads();
    }
}

// ---------------- hierarchical scan, phase 1: per-chunk sums ----------------
__global__ __launch_bounds__(256) void chunksum_kernel(const int* __restrict__ cnt, int n,
                                                       int* __restrict__ bsum) {
    __shared__ int red[256];
    int blk = blockIdx.x, tid = threadIdx.x;
    int base = blk * SCHUNK;
    int s = 0;
    for (int idx = tid; idx < SCHUNK; idx += 256) {
        int i = base + idx;
        s += (i < n) ? cnt[i] : 0;
    }
    red[tid] = s; __syncthreads();
    for (int off = 128; off > 0; off >>= 1) {
        if (tid < off) red[tid] += red[tid + off];
        __syncthreads();
    }
    if (tid == 0) bsum[blk] = red[0];
}

// ---------------- hierarchical scan, phase 3: apply ----------------
__global__ __launch_bounds__(256) void scan_apply_kernel(const int* __restrict__ cnt, int n,
                                                         const int* __restrict__ bstart,
                                                         int* __restrict__ start,
                                                         int* __restrict__ cursor,
                                                         float* __restrict__ dinv) {
    __shared__ int tsum[256];
    int blk = blockIdx.x, tid = threadIdx.x;
    int base = blk * SCHUNK + tid * 4;
    int v[4];
    #pragma unroll
    for (int k = 0; k < 4; k++) { int i = base + k; v[k] = (i < n) ? cnt[i] : 0; }
    int loc = v[0] + v[1] + v[2] + v[3];
    tsum[tid] = loc; __syncthreads();
    int x = loc;
    for (int off = 1; off < 256; off <<= 1) {
        int t = (tid >= off) ? tsum[tid - off] : 0;
        __syncthreads();
        x += t; tsum[tid] = x;
        __syncthreads();
    }
    int run = x - loc + bstart[blk];
    #pragma unroll
    for (int k = 0; k < 4; k++) {
        int i = base + k;
        if (i < n) {
            start[i]  = run;
            cursor[i] = run;
            dinv[i]   = rsqrtf((float)v[k] + 1.0f);
        }
        run += v[k];
    }
}

// ---------------- CSR fill (edges bucketed by dst, clamped) ----------------
__global__ void csr_fill_kernel(const int* __restrict__ src, const int* __restrict__ dst, int e, int n,
                                int* __restrict__ cursor, const float* __restrict__ dinv,
                                int* __restrict__ csr_src, float* __restrict__ csr_w) {
    int i = blockIdx.x * blockDim.x + threadIdx.x;
    if (i < e) {
        int s = src[i], d = dst[i];
        s = (s < 0) ? 0 : (s >= n ? n - 1 : s);
        d = (d < 0) ? 0 : (d >= n ? n - 1 : d);
        int pos = atomicAdd(&cursor[d], 1);
        csr_src[pos] = s;
        csr_w[pos]   = dinv[s] * dinv[d];
    }
}

// ---------------- fp32 GEMM: T[n,128] = A[n,:] (lda) @ W[128,128] ----------------
__global__ __launch_bounds__(256) void gemm_nk128(const float* __restrict__ A, int lda,
                                                  const float* __restrict__ W,
                                                  float* __restrict__ T, int n) {
    __shared__ float Al[64 * 128];   // XOR-swizzled along k
    __shared__ float Wl[128 * 64];
    int tid = threadIdx.x;
    int brow = blockIdx.x * 64;
    int chalf = blockIdx.y;          // 0/1 -> cols [0,64) or [64,128)

    for (int kk = tid >> 4; kk < 128; kk += 16) {
        int c4 = tid & 15;
        float4 w = *(const float4*)&W[kk * 128 + chalf * 64 + c4 * 4];
        *(float4*)&Wl[kk * 64 + c4 * 4] = w;
    }
    for (int idx = tid; idx < 64 * 128; idx += 256) {
        int rr = idx >> 7, k = idx & 127;
        int r = brow + rr;
        float a = (r < n) ? A[(size_t)r * lda + k] : 0.0f;
        Al[rr * 128 + (k ^ (rr & 31))] = a;
    }
    __syncthreads();

    int tr = tid >> 4, tc = tid & 15;
    int r0 = tr * 4;
    float acc[4][4] = {};
    #pragma unroll 4
    for (int k = 0; k < 128; k++) {
        float4 w = *(const float4*)&Wl[k * 64 + tc * 4];
        float a0 = Al[(r0 + 0) * 128 + (k ^ ((r0 + 0) & 31))];
        float a1 = Al[(r0 + 1) * 128 + (k ^ ((r0 + 1) & 31))];
        float a2 = Al[(r0 + 2) * 128 + (k ^ ((r0 + 2) & 31))];
        float a3 = Al[(r0 + 3) * 128 + (k ^ ((r0 + 3) & 31))];
        acc[0][0] += a0 * w.x; acc[0][1] += a0 * w.y; acc[0][2] += a0 * w.z; acc[0][3] += a0 * w.w;
        acc[1][0] += a1 * w.x; acc[1][1] += a1 * w.y; acc[1][2] += a1 * w.z; acc[1][3] += a1 * w.w;
        acc[2][0] += a2 * w.x; acc[2][1] += a2 * w.y; acc[2][2] += a2 * w.z; acc[2][3] += a2 * w.w;
        acc[3][0] += a3 * w.x; acc[3][1] += a3 * w.y; acc[3][2] += a3 * w.z; acc[3][3] += a3 * w.w;
    }
    for (int i = 0; i < 4; i++) {
        int r = brow + r0 + i;
        if (r < n) {
            float4 o = make_float4(acc[i][0], acc[i][1], acc[i][2], acc[i][3]);
            *(float4*)&T[(size_t)r * 128 + chalf * 64 + tc * 4] = o;
        }
    }
}

// ---------------- GCN aggregation (128-channel), pull-based, v2 ----------------
// 8 nodes per 256-thread block; 32 lanes per node, float4 per lane.
// vs v1 (1 node / 128-thread block): 8 independent edge streams per block and
// 1 load instruction per gathered row (was 2 wave-wide dword loads) -> more
// memory-level parallelism for the latency-bound random gather.
// Per-channel accumulation order identical to v1 (self, then CSR order).
// T3 epilogue replicates v1's 128-leaf reduction tree exactly:
// lane shuffles = channel bits 6..2, then (x+z)+(y+w) = bits 1..0.
__global__ __launch_bounds__(256) void gcn_agg128(const float* __restrict__ T,
                                                  const int* __restrict__ csr_src,
                                                  const float* __restrict__ csr_w,
                                                  const int* __restrict__ row_start,
                                                  const int* __restrict__ cnt,
                                                  const float* __restrict__ dinv,
                                                  const float* __restrict__ bias,
                                                  float* __restrict__ feat, int layer, int n,
                                                  const float* __restrict__ Wg3,
                                                  float* __restrict__ T3) {
    int g    = threadIdx.x >> 5;          // node group 0..7
    int lane = threadIdx.x & 31;
    int i = blockIdx.x * AGG_NPB + g;
    if (i >= n) return;                   // no barriers below -> safe divergence
    int c4 = lane << 2;                   // channel base (16B aligned in T)
    float di = dinv[i];
    float s2 = di * di;
    float4 self = *(const float4*)&T[(size_t)i * 128 + c4];
    float4 acc = make_float4(self.x * s2, self.y * s2, self.z * s2, self.w * s2);
    int rs = row_start[i], ce = cnt[i];
    for (int e = 0; e < ce; e++) {
        int s  = csr_src[rs + e];
        float w = csr_w[rs + e];
        float4 v = *(const float4*)&T[(size_t)s * 128 + c4];
        acc.x += v.x * w; acc.y += v.y * w; acc.z += v.z * w; acc.w += v.w * w;
    }
    float4 bb = *(const float4*)&bias[c4];
    float4 vt = make_float4(tanhf(acc.x + bb.x), tanhf(acc.y + bb.y),
                            tanhf(acc.z + bb.z), tanhf(acc.w + bb.w));
    float* fout = &feat[(size_t)i * D_TOT + layer * 128 + c4];  // base not 16B aligned
    fout[0] = vt.x; fout[1] = vt.y; fout[2] = vt.z; fout[3] = vt.w;
    if (T3 != nullptr) {                  // uniform branch (layer 2 only)
        float4 wg = *(const float4*)&Wg3[c4];
        float4 p = make_float4(vt.x * wg.x, vt.y * wg.y, vt.z * wg.z, vt.w * wg.w);
        #pragma unroll
        for (int off = 16; off > 0; off >>= 1) {
            p.x += __shfl_down(p.x, off, 32);
            p.y += __shfl_down(p.y, off, 32);
            p.z += __shfl_down(p.z, off, 32);
            p.w += __shfl_down(p.w, off, 32);
        }
        if (lane == 0) T3[i] = (p.x + p.z) + (p.y + p.w);
    }
}

// ---------------- layer 3 aggregation (1 channel) ----------------
__global__ void gcn_agg1(const float* __restrict__ T3,
                         const int* __restrict__ csr_src, const float* __restrict__ csr_w,
                         const int* __restrict__ row_start, const int* __restrict__ cnt,
                         const float* __restrict__ dinv, const float* __restrict__ bg3,
                         float* __restrict__ feat, int n) {
    int i = blockIdx.x * blockDim.x + threadIdx.x;
    if (i >= n) return;
    float di = dinv[i];
    float acc = T3[i] * di * di;
    int rs = row_start[i], ce = cnt[i];
    for (int e = 0; e < ce; e++) acc += T3[csr_src[rs + e]] * csr_w[rs + e];
    feat[(size_t)i * D_TOT + (D_TOT - 1)] = tanhf(acc + bg3[0]);
}

// ---------------- sort-pool: per-graph bitonic sort ----------------
// EXACT reference semantics: stable ascending argsort of fp32 key
//   key = 4.0f*(float)b - feat[:,-1]
__global__ __launch_bounds__(256) void sortpool_kernel(const float* __restrict__ feat,
                                                       const int* __restrict__ gcnt,
                                                       const int* __restrict__ gstart,
                                                       int* __restrict__ sel) {
    int b = blockIdx.x, tid = threadIdx.x;
    __shared__ float sv[SORT_CAP];
    __shared__ int   si[SORT_CAP];
    int cnt = gcnt[b];
    if (cnt > SORT_CAP) cnt = SORT_CAP;
    int start = gstart[b];
    if (cnt == 0) {
        for (int j = tid; j < KTOP; j += 256) sel[b * KTOP + j] = -1;
        return;
    }
    float bb = 4.0f * (float)b;    // exact in fp32
    int P = 1; while (P < cnt) P <<= 1;
    for (int j = tid; j < P; j += 256) {
        if (j < cnt) {
            float v = feat[(size_t)(start + j) * D_TOT + (D_TOT - 1)];
            sv[j] = bb - v;        // single fp32 rounding, matches reference
            si[j] = j;
        } else { sv[j] = FLT_MAX; si[j] = j; }
    }
    __syncthreads();
    for (int ksz = 2; ksz <= P; ksz <<= 1) {
        for (int jj = ksz >> 1; jj > 0; jj >>= 1) {
            for (int t = tid; t < P; t += 256) {
                int l = t ^ jj;
                if (l > t) {
                    float va = sv[t], vb = sv[l];
                    int   ia = si[t], ib = si[l];
                    bool aFirst = (va < vb) || (va == vb && ia < ib);
                    bool up = ((t & ksz) == 0);
                    if (up ? !aFirst : aFirst) {
                        sv[t] = vb; sv[l] = va; si[t] = ib; si[l] = ia;
                    }
                }
            }
            __syncthreads();
        }
    }
    for (int j = tid; j < KTOP; j += 256)
        sel[b * KTOP + j] = (j < cnt) ? (start + si[j]) : -1;
}

// ---------------- conv1: LDS-staged, coalesced, float4 ----------------
__global__ __launch_bounds__(256) void conv1_kernel(const float* __restrict__ feat,
                                                    const int* __restrict__ sel,
                                                    const float* __restrict__ W1,
                                                    const float* __restrict__ b1,
                                                    float* __restrict__ h1, int nslots) {
    __shared__ float W1l[C1 * D_PAD];        // 24832 B
    __shared__ float rows[C1SLOTS * D_PAD];  // 49664 B
    int tid = threadIdx.x;
    int base = blockIdx.x * C1SLOTS;

    for (int idx = tid; idx < C1 * D_TOT; idx += 256) {
        int o = idx / D_TOT, t = idx - o * D_TOT;
        W1l[o * D_PAD + t] = W1[idx];
    }
    for (int idx = tid; idx < C1SLOTS * D_TOT; idx += 256) {
        int r = idx / D_TOT, t = idx - r * D_TOT;
        int slot = base + r;
        float v = 0.f;
        if (slot < nslots) {
            int row = sel[slot];
            if (row >= 0) v = feat[(size_t)row * D_TOT + t];
        }
        rows[r * D_PAD + t] = v;
    }
    __syncthreads();

    int g = tid >> 4, o = tid & 15;   // g: 0..15 -> rows 2g, 2g+1
    int r0 = 2 * g;
    const float* wr = &W1l[o * D_PAD];
    const float* p0 = &rows[r0 * D_PAD];
    const float* p1 = &rows[(r0 + 1) * D_PAD];
    float a0 = 0.f, a1 = 0.f;
    #pragma unroll 4
    for (int t = 0; t < 384; t += 4) {
        float4 w  = *(const float4*)&wr[t];
        float4 x0 = *(const float4*)&p0[t];
        float4 x1 = *(const float4*)&p1[t];
        a0 += x0.x * w.x + x0.y * w.y + x0.z * w.z + x0.w * w.w;
        a1 += x1.x * w.x + x1.y * w.y + x1.z * w.z + x1.w * w.w;
    }
    a0 += p0[384] * wr[384];
    a1 += p1[384] * wr[384];

    float bo = b1[o];
    int slot0 = base + r0;
    if (slot0 < nslots) {
        int b = slot0 / KTOP, j = slot0 - b * KTOP;
        h1[((size_t)b * C1 + o) * KTOP + j] = fmaxf(a0 + bo, 0.f);
    }
    int slot1 = slot0 + 1;
    if (slot1 < nslots) {
        int b = slot1 / KTOP, j = slot1 - b * KTOP;
        h1[((size_t)b * C1 + o) * KTOP + j] = fmaxf(a1 + bo, 0.f);
    }
}

// ---------------- head: maxpool + conv2 + MLP, one block per graph ----------------
__global__ __launch_bounds__(256) void head_kernel(const float* __restrict__ h1,
                                                   const float* __restrict__ W2, const float* __restrict__ b2,
                                                   const float* __restrict__ Wm1, const float* __restrict__ bm1,
                                                   const float* __restrict__ Wm2, const float* __restrict__ bm2,
                                                   float* __restrict__ out) {
    int b = blockIdx.x, tid = threadIdx.x;
    __shared__ float pool[C1 * POOLW];   // 800
    __shared__ float flat[DENSE];        // 1472
    __shared__ float hid[MLPH];          // 128
    __shared__ float red[256];

    for (int p = tid; p < C1 * POOLW; p += 256) {
        int i = p / POOLW, t = p % POOLW;
        float v0 = h1[((size_t)b * C1 + i) * KTOP + 2 * t];
        float v1 = h1[((size_t)b * C1 + i) * KTOP + 2 * t + 1];
        pool[i * POOLW + t] = fmaxf(v0, v1);
    }
    __syncthreads();
    for (int q = tid; q < DENSE; q += 256) {
        int o = q / CONV2W, t = q % CONV2W;
        float acc = b2[o];
        #pragma unroll
        for (int i = 0; i < C1; i++) {
            #pragma unroll
            for (int ks = 0; ks < KW2; ks++)
                acc += pool[i * POOLW + t + ks] * W2[(o * C1 + i) * KW2 + ks];
        }
        flat[o * CONV2W + t] = fmaxf(acc, 0.f);
    }
    __syncthreads();
    {
        int h = tid & 127, part = tid >> 7;     // 2 partials per output
        float acc = 0.f;
        for (int t = part * (DENSE / 2); t < (part + 1) * (DENSE / 2); t++)
            acc += flat[t] * Wm1[(size_t)t * MLPH + h];
        red[tid] = acc;
    }
    __syncthreads();
    if (tid < 128) hid[tid] = fmaxf(red[tid] + red[tid + 128] + bm1[tid], 0.f);
    __syncthreads();
    if (tid < 64) {
        float p = hid[tid] * Wm2[tid] + hid[tid + 64] * Wm2[tid + 64];
        #pragma unroll
        for (int off = 32; off > 0; off >>= 1) p += __shfl_down(p, off, 64);
        if (tid == 0) out[b] = p + bm2[0];
    }
}

// ================= launch =================
extern "C" void kernel_launch(void* const* d_in, const int* in_sizes, int n_in,
                              void* d_out, int out_size, void* d_ws, size_t ws_size,
                              hipStream_t stream) {
    const float* x     = (const float*)d_in[0];
    const int*   ei    = (const int*)d_in[1];
    const int*   batch = (const int*)d_in[2];
    const float* Wg0 = (const float*)d_in[4],  *bg0 = (const float*)d_in[5];
    const float* Wg1 = (const float*)d_in[6],  *bg1 = (const float*)d_in[7];
    const float* Wg2 = (const float*)d_in[8],  *bg2 = (const float*)d_in[9];
    const float* Wg3 = (const float*)d_in[10], *bg3 = (const float*)d_in[11];
    const float* W1  = (const float*)d_in[12], *b1  = (const float*)d_in[13];
    const float* W2  = (const float*)d_in[14], *b2  = (const float*)d_in[15];
    const float* Wm1 = (const float*)d_in[16], *bm1 = (const float*)d_in[17];
    const float* Wm2 = (const float*)d_in[18], *bm2 = (const float*)d_in[19];
    float* out = (float*)d_out;

    const int N = in_sizes[2];        // batch has N elements
    const int E = in_sizes[1] / 2;
    const int B = out_size;           // 512
    const int* src = ei;
    const int* dst = ei + E;
    const int nb = (N + SCHUNK - 1) / SCHUNK;

    // ---- workspace budget check ----
    auto rup = [](size_t b) { return (b + 255) & ~(size_t)255; };
    size_t need = 0;
    need += rup((size_t)N * 4) * 4;                 // cnt_node,row_start,cursor,dinv
    need += rup((size_t)N * 4);                     // T3
    need += rup((size_t)nb * 4) * 2;                // bsum,bstart
    need += rup((size_t)B * 4) * 2;                 // gcnt,gstart
    need += rup((size_t)E * 4) * 2;                 // csr_src,csr_w
    need += rup((size_t)N * 128 * 4);               // T
    need += rup((size_t)N * D_TOT * 4);             // feat
    need += rup((size_t)B * KTOP * 4);              // sel
    need += rup((size_t)B * C1 * KTOP * 4);         // h1
    if (need > ws_size) {
        hipMemsetAsync(d_out, 0, (size_t)out_size * 4, stream);
        return;
    }

    // workspace carve
    char* p = (char*)d_ws;
    auto alloc = [&](size_t bytes) { void* r = (void*)p; p += (bytes + 255) & ~(size_t)255; return r; };
    int*   cnt_node  = (int*)alloc((size_t)N * 4);
    int*   row_start = (int*)alloc((size_t)N * 4);
    int*   cursor    = (int*)alloc((size_t)N * 4);
    float* dinv      = (float*)alloc((size_t)N * 4);
    float* T3        = (float*)alloc((size_t)N * 4);
    int*   bsum      = (int*)alloc((size_t)nb * 4);
    int*   bstart    = (int*)alloc((size_t)nb * 4);
    int*   gcnt      = (int*)alloc((size_t)B * 4);
    int*   gstart    = (int*)alloc((size_t)B * 4);
    int*   csr_src   = (int*)alloc((size_t)E * 4);
    float* csr_w     = (float*)alloc((size_t)E * 4);
    float* T         = (float*)alloc((size_t)N * 128 * 4);
    float* feat      = (float*)alloc((size_t)N * D_TOT * 4);
    int*   sel       = (int*)alloc((size_t)B * KTOP * 4);
    float* h1        = (float*)alloc((size_t)B * C1 * KTOP * 4);

    hipMemsetAsync(cnt_node, 0, (size_t)N * 4, stream);
    hipMemsetAsync(gcnt,     0, (size_t)B * 4, stream);

    hist_kernel<<<(E + 255) / 256, 256, 0, stream>>>(dst, E, N, cnt_node);
    hist_kernel<<<(N + 255) / 256, 256, 0, stream>>>(batch, N, B, gcnt);

    // hierarchical exclusive scan over node degrees
    chunksum_kernel<<<nb, 256, 0, stream>>>(cnt_node, N, bsum);
    scan_excl_kernel<<<1, 1024, 0, stream>>>(bsum, nb, bstart, nullptr, nullptr);
    scan_apply_kernel<<<nb, 256, 0, stream>>>(cnt_node, N, bstart, row_start, cursor, dinv);
    // per-graph counts: B=512 -> single chunk, keep simple scan
    scan_excl_kernel<<<1, 1024, 0, stream>>>(gcnt, B, gstart, nullptr, nullptr);

    csr_fill_kernel<<<(E + 255) / 256, 256, 0, stream>>>(src, dst, E, N, cursor, dinv, csr_src, csr_w);

    dim3 ggrid((N + 63) / 64, 2);
    const int agg_grid = (N + AGG_NPB - 1) / AGG_NPB;
    // layer 0: x(F=128) -> feat cols [0,128)
    gemm_nk128<<<ggrid, 256, 0, stream>>>(x, F_IN, Wg0, T, N);
    gcn_agg128<<<agg_grid, 256, 0, stream>>>(T, csr_src, csr_w, row_start, cnt_node, dinv, bg0, feat, 0, N, nullptr, nullptr);
    // layer 1: feat cols [0,128) -> [128,256)
    gemm_nk128<<<ggrid, 256, 0, stream>>>(feat, D_TOT, Wg1, T, N);
    gcn_agg128<<<agg_grid, 256, 0, stream>>>(T, csr_src, csr_w, row_start, cnt_node, dinv, bg1, feat, 1, N, nullptr, nullptr);
    // layer 2: feat cols [128,256) -> [256,384), fused with layer-3 GEMV -> T3
    gemm_nk128<<<ggrid, 256, 0, stream>>>(feat + 128, D_TOT, Wg2, T, N);
    gcn_agg128<<<agg_grid, 256, 0, stream>>>(T, csr_src, csr_w, row_start, cnt_node, dinv, bg2, feat, 2, N, Wg3, T3);
    // layer 3 aggregation (1 channel)
    gcn_agg1<<<(N + 255) / 256, 256, 0, stream>>>(T3, csr_src, csr_w, row_start, cnt_node, dinv, bg3, feat, N);

    sortpool_kernel<<<B, 256, 0, stream>>>(feat, gcnt, gstart, sel);
    conv1_kernel<<<(B * KTOP + C1SLOTS - 1) / C1SLOTS, 256, 0, stream>>>(feat, sel, W1, b1, h1, B * KTOP);
    head_kernel<<<B, 256, 0, stream>>>(h1, W2, b2, Wm1, bm1, Wm2, bm2, out);
}

// Round 14
// 1188.646 us; speedup vs baseline: 1.7022x; 1.1754x over previous
//
#include <hip/hip_runtime.h>
#include <hip/hip_bf16.h>
#include <cfloat>

// Problem constants (match reference)
#define F_IN   128
#define H_DIM  128
#define D_TOT  385          // H*L + 1 (logical feature dim)
#define FSTR   388          // padded feat row stride (16B-aligned float4 rows)
#define KTOP   100
#define C1     16
#define C2     32
#define KW2    5
#define POOLW  (KTOP/2)             // 50
#define CONV2W (POOLW - KW2 + 1)    // 46
#define DENSE  (C2*CONV2W)          // 1472
#define MLPH   128
#define SORT_CAP 2048
#define D_PAD  388                  // conv1 LDS row pad
#define C1SLOTS 32                  // rows per conv1 block
#define SCHUNK 1024                 // scan chunk
#define AGG_NPB 8                   // nodes per aggregation block

// ---------------- histogram (int32 keys, clamped) ----------------
__global__ void hist_kernel(const int* __restrict__ keys, int n, int nbins, int* __restrict__ cnt) {
    int i = blockIdx.x * blockDim.x + threadIdx.x;
    if (i < n) {
        int k = keys[i];
        k = (k < 0) ? 0 : (k >= nbins ? nbins - 1 : k);
        atomicAdd(&cnt[k], 1);
    }
}

// ---------------- single-block exclusive scan (small n / chunk sums) ----------------
__global__ void scan_excl_kernel(const int* __restrict__ cnt, int n,
                                 int* __restrict__ start, int* __restrict__ cursor,
                                 float* __restrict__ dinv) {
    __shared__ int s[1024];
    __shared__ int carry_s;
    int tid = threadIdx.x;
    if (tid == 0) carry_s = 0;
    __syncthreads();
    for (int base = 0; base < n; base += 1024) {
        int i = base + tid;
        int v = (i < n) ? cnt[i] : 0;
        s[tid] = v;
        __syncthreads();
        for (int off = 1; off < 1024; off <<= 1) {
            int t = (tid >= off) ? s[tid - off] : 0;
            __syncthreads();
            s[tid] += t;
            __syncthreads();
        }
        int excl = s[tid] - v;
        int carry = carry_s;
        if (i < n) {
            start[i] = carry + excl;
            if (cursor) cursor[i] = carry + excl;
            if (dinv)   dinv[i]   = rsqrtf((float)v + 1.0f);
        }
        __syncthreads();
        if (tid == 0) carry_s += s[1023];
        __syncthreads();
    }
}

// ---------------- hierarchical scan, phase 1: per-chunk sums ----------------
__global__ __launch_bounds__(256) void chunksum_kernel(const int* __restrict__ cnt, int n,
                                                       int* __restrict__ bsum) {
    __shared__ int red[256];
    int blk = blockIdx.x, tid = threadIdx.x;
    int base = blk * SCHUNK;
    int s = 0;
    for (int idx = tid; idx < SCHUNK; idx += 256) {
        int i = base + idx;
        s += (i < n) ? cnt[i] : 0;
    }
    red[tid] = s; __syncthreads();
    for (int off = 128; off > 0; off >>= 1) {
        if (tid < off) red[tid] += red[tid + off];
        __syncthreads();
    }
    if (tid == 0) bsum[blk] = red[0];
}

// ---------------- hierarchical scan, phase 3: apply ----------------
__global__ __launch_bounds__(256) void scan_apply_kernel(const int* __restrict__ cnt, int n,
                                                         const int* __restrict__ bstart,
                                                         int* __restrict__ start,
                                                         int* __restrict__ cursor,
                                                         float* __restrict__ dinv) {
    __shared__ int tsum[256];
    int blk = blockIdx.x, tid = threadIdx.x;
    int base = blk * SCHUNK + tid * 4;
    int v[4];
    #pragma unroll
    for (int k = 0; k < 4; k++) { int i = base + k; v[k] = (i < n) ? cnt[i] : 0; }
    int loc = v[0] + v[1] + v[2] + v[3];
    tsum[tid] = loc; __syncthreads();
    int x = loc;
    for (int off = 1; off < 256; off <<= 1) {
        int t = (tid >= off) ? tsum[tid - off] : 0;
        __syncthreads();
        x += t; tsum[tid] = x;
        __syncthreads();
    }
    int run = x - loc + bstart[blk];
    #pragma unroll
    for (int k = 0; k < 4; k++) {
        int i = base + k;
        if (i < n) {
            start[i]  = run;
            cursor[i] = run;
            dinv[i]   = rsqrtf((float)v[k] + 1.0f);
        }
        run += v[k];
    }
}

// ---------------- CSR fill (edges bucketed by dst, clamped) ----------------
__global__ void csr_fill_kernel(const int* __restrict__ src, const int* __restrict__ dst, int e, int n,
                                int* __restrict__ cursor, const float* __restrict__ dinv,
                                int* __restrict__ csr_src, float* __restrict__ csr_w) {
    int i = blockIdx.x * blockDim.x + threadIdx.x;
    if (i < e) {
        int s = src[i], d = dst[i];
        s = (s < 0) ? 0 : (s >= n ? n - 1 : s);
        d = (d < 0) ? 0 : (d >= n ? n - 1 : d);
        int pos = atomicAdd(&cursor[d], 1);
        csr_src[pos] = s;
        csr_w[pos]   = dinv[s] * dinv[d];
    }
}

// ---------------- fp32 GEMM v2: T[n,128] = A[n,:](lda) @ W[128,128] ----------------
// v1 (160 us): A+W both in LDS (64 KiB -> 2 blocks/CU, 21% occupancy), 5 LDS
// instr/k -> latency-bound at VALUBusy 33%.
// v2: only W-half in LDS (32 KiB -> 5 blocks/CU, ~62% occupancy); A read
// directly from global as float4 along k (16-lane broadcast; A is L2/L3-hot).
// k processed 4 at a time: 4 global b128 + 4 LDS b128 + 64 FMA.
// Per-output k-order identical to v1 -> bit-identical results.
// Requires lda*4 % 16 == 0 (lda=128 or FSTR=388).
__global__ __launch_bounds__(256) void gemm_nk128(const float* __restrict__ A, int lda,
                                                  const float* __restrict__ W,
                                                  float* __restrict__ T, int n) {
    __shared__ float Wl[128 * 64];
    int tid = threadIdx.x;
    int brow = blockIdx.x * 64;
    int chalf = blockIdx.y;          // 0/1 -> cols [0,64) or [64,128)

    for (int kk = tid >> 4; kk < 128; kk += 16) {
        int c4 = tid & 15;
        float4 w = *(const float4*)&W[kk * 128 + chalf * 64 + c4 * 4];
        *(float4*)&Wl[kk * 64 + c4 * 4] = w;
    }
    __syncthreads();

    int tr = tid >> 4, tc = tid & 15;
    int r0 = brow + tr * 4;
    int c0 = tc * 4;
    // clamp row pointers (values unused when r >= n; stores guarded)
    const float* pa0 = A + (size_t)((r0 + 0 < n) ? r0 + 0 : n - 1) * lda;
    const float* pa1 = A + (size_t)((r0 + 1 < n) ? r0 + 1 : n - 1) * lda;
    const float* pa2 = A + (size_t)((r0 + 2 < n) ? r0 + 2 : n - 1) * lda;
    const float* pa3 = A + (size_t)((r0 + 3 < n) ? r0 + 3 : n - 1) * lda;

    float acc[4][4] = {};
    #pragma unroll 8
    for (int kk = 0; kk < 128; kk += 4) {
        float4 a0 = *(const float4*)&pa0[kk];
        float4 a1 = *(const float4*)&pa1[kk];
        float4 a2 = *(const float4*)&pa2[kk];
        float4 a3 = *(const float4*)&pa3[kk];
        float4 w0 = *(const float4*)&Wl[(kk + 0) * 64 + c0];
        float4 w1 = *(const float4*)&Wl[(kk + 1) * 64 + c0];
        float4 w2 = *(const float4*)&Wl[(kk + 2) * 64 + c0];
        float4 w3 = *(const float4*)&Wl[(kk + 3) * 64 + c0];
        // k-sequential accumulation per output (bit-identical to v1)
        #define ROWFMA(i, ai)                                              \
            acc[i][0] += ai.x * w0.x; acc[i][1] += ai.x * w0.y;            \
            acc[i][2] += ai.x * w0.z; acc[i][3] += ai.x * w0.w;            \
            acc[i][0] += ai.y * w1.x; acc[i][1] += ai.y * w1.y;            \
            acc[i][2] += ai.y * w1.z; acc[i][3] += ai.y * w1.w;            \
            acc[i][0] += ai.z * w2.x; acc[i][1] += ai.z * w2.y;            \
            acc[i][2] += ai.z * w2.z; acc[i][3] += ai.z * w2.w;            \
            acc[i][0] += ai.w * w3.x; acc[i][1] += ai.w * w3.y;            \
            acc[i][2] += ai.w * w3.z; acc[i][3] += ai.w * w3.w;
        ROWFMA(0, a0) ROWFMA(1, a1) ROWFMA(2, a2) ROWFMA(3, a3)
        #undef ROWFMA
    }
    for (int i = 0; i < 4; i++) {
        int r = brow + tr * 4 + i;
        if (r < n) {
            float4 o = make_float4(acc[i][0], acc[i][1], acc[i][2], acc[i][3]);
            *(float4*)&T[(size_t)r * 128 + chalf * 64 + c0] = o;
        }
    }
}

// ---------------- GCN aggregation (128-channel), pull-based ----------------
// 8 nodes per 256-thread block; 32 lanes per node, float4 per lane.
__global__ __launch_bounds__(256) void gcn_agg128(const float* __restrict__ T,
                                                  const int* __restrict__ csr_src,
                                                  const float* __restrict__ csr_w,
                                                  const int* __restrict__ row_start,
                                                  const int* __restrict__ cnt,
                                                  const float* __restrict__ dinv,
                                                  const float* __restrict__ bias,
                                                  float* __restrict__ feat, int layer, int n,
                                                  const float* __restrict__ Wg3,
                                                  float* __restrict__ T3) {
    int g    = threadIdx.x >> 5;          // node group 0..7
    int lane = threadIdx.x & 31;
    int i = blockIdx.x * AGG_NPB + g;
    if (i >= n) return;                   // no barriers below -> safe divergence
    int c4 = lane << 2;                   // channel base (16B aligned in T)
    float di = dinv[i];
    float s2 = di * di;
    float4 self = *(const float4*)&T[(size_t)i * 128 + c4];
    float4 acc = make_float4(self.x * s2, self.y * s2, self.z * s2, self.w * s2);
    int rs = row_start[i], ce = cnt[i];
    for (int e = 0; e < ce; e++) {
        int s  = csr_src[rs + e];
        float w = csr_w[rs + e];
        float4 v = *(const float4*)&T[(size_t)s * 128 + c4];
        acc.x += v.x * w; acc.y += v.y * w; acc.z += v.z * w; acc.w += v.w * w;
    }
    float4 bb = *(const float4*)&bias[c4];
    float4 vt = make_float4(tanhf(acc.x + bb.x), tanhf(acc.y + bb.y),
                            tanhf(acc.z + bb.z), tanhf(acc.w + bb.w));
    // FSTR=388 -> 16B-aligned float4 store
    *(float4*)&feat[(size_t)i * FSTR + layer * 128 + c4] = vt;
    if (T3 != nullptr) {                  // uniform branch (layer 2 only)
        float4 wg = *(const float4*)&Wg3[c4];
        float4 p = make_float4(vt.x * wg.x, vt.y * wg.y, vt.z * wg.z, vt.w * wg.w);
        #pragma unroll
        for (int off = 16; off > 0; off >>= 1) {
            p.x += __shfl_down(p.x, off, 32);
            p.y += __shfl_down(p.y, off, 32);
            p.z += __shfl_down(p.z, off, 32);
            p.w += __shfl_down(p.w, off, 32);
        }
        if (lane == 0) T3[i] = (p.x + p.z) + (p.y + p.w);
    }
}

// ---------------- layer 3 aggregation (1 channel) ----------------
__global__ void gcn_agg1(const float* __restrict__ T3,
                         const int* __restrict__ csr_src, const float* __restrict__ csr_w,
                         const int* __restrict__ row_start, const int* __restrict__ cnt,
                         const float* __restrict__ dinv, const float* __restrict__ bg3,
                         float* __restrict__ feat, int n) {
    int i = blockIdx.x * blockDim.x + threadIdx.x;
    if (i >= n) return;
    float di = dinv[i];
    float acc = T3[i] * di * di;
    int rs = row_start[i], ce = cnt[i];
    for (int e = 0; e < ce; e++) acc += T3[csr_src[rs + e]] * csr_w[rs + e];
    feat[(size_t)i * FSTR + (D_TOT - 1)] = tanhf(acc + bg3[0]);
}

// ---------------- sort-pool: per-graph bitonic sort ----------------
// EXACT reference semantics: stable ascending argsort of fp32 key
//   key = 4.0f*(float)b - feat[:,-1]
__global__ __launch_bounds__(256) void sortpool_kernel(const float* __restrict__ feat,
                                                       const int* __restrict__ gcnt,
                                                       const int* __restrict__ gstart,
                                                       int* __restrict__ sel) {
    int b = blockIdx.x, tid = threadIdx.x;
    __shared__ float sv[SORT_CAP];
    __shared__ int   si[SORT_CAP];
    int cnt = gcnt[b];
    if (cnt > SORT_CAP) cnt = SORT_CAP;
    int start = gstart[b];
    if (cnt == 0) {
        for (int j = tid; j < KTOP; j += 256) sel[b * KTOP + j] = -1;
        return;
    }
    float bb = 4.0f * (float)b;    // exact in fp32
    int P = 1; while (P < cnt) P <<= 1;
    for (int j = tid; j < P; j += 256) {
        if (j < cnt) {
            float v = feat[(size_t)(start + j) * FSTR + (D_TOT - 1)];
            sv[j] = bb - v;        // single fp32 rounding, matches reference
            si[j] = j;
        } else { sv[j] = FLT_MAX; si[j] = j; }
    }
    __syncthreads();
    for (int ksz = 2; ksz <= P; ksz <<= 1) {
        for (int jj = ksz >> 1; jj > 0; jj >>= 1) {
            for (int t = tid; t < P; t += 256) {
                int l = t ^ jj;
                if (l > t) {
                    float va = sv[t], vb = sv[l];
                    int   ia = si[t], ib = si[l];
                    bool aFirst = (va < vb) || (va == vb && ia < ib);
                    bool up = ((t & ksz) == 0);
                    if (up ? !aFirst : aFirst) {
                        sv[t] = vb; sv[l] = va; si[t] = ib; si[l] = ia;
                    }
                }
            }
            __syncthreads();
        }
    }
    for (int j = tid; j < KTOP; j += 256)
        sel[b * KTOP + j] = (j < cnt) ? (start + si[j]) : -1;
}

// ---------------- conv1: LDS-staged, coalesced, float4 ----------------
__global__ __launch_bounds__(256) void conv1_kernel(const float* __restrict__ feat,
                                                    const int* __restrict__ sel,
                                                    const float* __restrict__ W1,
                                                    const float* __restrict__ b1,
                                                    float* __restrict__ h1, int nslots) {
    __shared__ float W1l[C1 * D_PAD];        // 24832 B
    __shared__ float rows[C1SLOTS * D_PAD];  // 49664 B
    int tid = threadIdx.x;
    int base = blockIdx.x * C1SLOTS;

    for (int idx = tid; idx < C1 * D_TOT; idx += 256) {
        int o = idx / D_TOT, t = idx - o * D_TOT;
        W1l[o * D_PAD + t] = W1[idx];
    }
    for (int idx = tid; idx < C1SLOTS * D_TOT; idx += 256) {
        int r = idx / D_TOT, t = idx - r * D_TOT;
        int slot = base + r;
        float v = 0.f;
        if (slot < nslots) {
            int row = sel[slot];
            if (row >= 0) v = feat[(size_t)row * FSTR + t];
        }
        rows[r * D_PAD + t] = v;
    }
    __syncthreads();

    int g = tid >> 4, o = tid & 15;   // g: 0..15 -> rows 2g, 2g+1
    int r0 = 2 * g;
    const float* wr = &W1l[o * D_PAD];
    const float* p0 = &rows[r0 * D_PAD];
    const float* p1 = &rows[(r0 + 1) * D_PAD];
    float a0 = 0.f, a1 = 0.f;
    #pragma unroll 4
    for (int t = 0; t < 384; t += 4) {
        float4 w  = *(const float4*)&wr[t];
        float4 x0 = *(const float4*)&p0[t];
        float4 x1 = *(const float4*)&p1[t];
        a0 += x0.x * w.x + x0.y * w.y + x0.z * w.z + x0.w * w.w;
        a1 += x1.x * w.x + x1.y * w.y + x1.z * w.z + x1.w * w.w;
    }
    a0 += p0[384] * wr[384];
    a1 += p1[384] * wr[384];

    float bo = b1[o];
    int slot0 = base + r0;
    if (slot0 < nslots) {
        int b = slot0 / KTOP, j = slot0 - b * KTOP;
        h1[((size_t)b * C1 + o) * KTOP + j] = fmaxf(a0 + bo, 0.f);
    }
    int slot1 = slot0 + 1;
    if (slot1 < nslots) {
        int b = slot1 / KTOP, j = slot1 - b * KTOP;
        h1[((size_t)b * C1 + o) * KTOP + j] = fmaxf(a1 + bo, 0.f);
    }
}

// ---------------- head: maxpool + conv2 + MLP, one block per graph ----------------
__global__ __launch_bounds__(256) void head_kernel(const float* __restrict__ h1,
                                                   const float* __restrict__ W2, const float* __restrict__ b2,
                                                   const float* __restrict__ Wm1, const float* __restrict__ bm1,
                                                   const float* __restrict__ Wm2, const float* __restrict__ bm2,
                                                   float* __restrict__ out) {
    int b = blockIdx.x, tid = threadIdx.x;
    __shared__ float pool[C1 * POOLW];   // 800
    __shared__ float flat[DENSE];        // 1472
    __shared__ float hid[MLPH];          // 128
    __shared__ float red[256];

    for (int p = tid; p < C1 * POOLW; p += 256) {
        int i = p / POOLW, t = p % POOLW;
        float v0 = h1[((size_t)b * C1 + i) * KTOP + 2 * t];
        float v1 = h1[((size_t)b * C1 + i) * KTOP + 2 * t + 1];
        pool[i * POOLW + t] = fmaxf(v0, v1);
    }
    __syncthreads();
    for (int q = tid; q < DENSE; q += 256) {
        int o = q / CONV2W, t = q % CONV2W;
        float acc = b2[o];
        #pragma unroll
        for (int i = 0; i < C1; i++) {
            #pragma unroll
            for (int ks = 0; ks < KW2; ks++)
                acc += pool[i * POOLW + t + ks] * W2[(o * C1 + i) * KW2 + ks];
        }
        flat[o * CONV2W + t] = fmaxf(acc, 0.f);
    }
    __syncthreads();
    {
        int h = tid & 127, part = tid >> 7;     // 2 partials per output
        float acc = 0.f;
        for (int t = part * (DENSE / 2); t < (part + 1) * (DENSE / 2); t++)
            acc += flat[t] * Wm1[(size_t)t * MLPH + h];
        red[tid] = acc;
    }
    __syncthreads();
    if (tid < 128) hid[tid] = fmaxf(red[tid] + red[tid + 128] + bm1[tid], 0.f);
    __syncthreads();
    if (tid < 64) {
        float p = hid[tid] * Wm2[tid] + hid[tid + 64] * Wm2[tid + 64];
        #pragma unroll
        for (int off = 32; off > 0; off >>= 1) p += __shfl_down(p, off, 64);
        if (tid == 0) out[b] = p + bm2[0];
    }
}

// ================= launch =================
extern "C" void kernel_launch(void* const* d_in, const int* in_sizes, int n_in,
                              void* d_out, int out_size, void* d_ws, size_t ws_size,
                              hipStream_t stream) {
    const float* x     = (const float*)d_in[0];
    const int*   ei    = (const int*)d_in[1];
    const int*   batch = (const int*)d_in[2];
    const float* Wg0 = (const float*)d_in[4],  *bg0 = (const float*)d_in[5];
    const float* Wg1 = (const float*)d_in[6],  *bg1 = (const float*)d_in[7];
    const float* Wg2 = (const float*)d_in[8],  *bg2 = (const float*)d_in[9];
    const float* Wg3 = (const float*)d_in[10], *bg3 = (const float*)d_in[11];
    const float* W1  = (const float*)d_in[12], *b1  = (const float*)d_in[13];
    const float* W2  = (const float*)d_in[14], *b2  = (const float*)d_in[15];
    const float* Wm1 = (const float*)d_in[16], *bm1 = (const float*)d_in[17];
    const float* Wm2 = (const float*)d_in[18], *bm2 = (const float*)d_in[19];
    float* out = (float*)d_out;

    const int N = in_sizes[2];        // batch has N elements
    const int E = in_sizes[1] / 2;
    const int B = out_size;           // 512
    const int* src = ei;
    const int* dst = ei + E;
    const int nb = (N + SCHUNK - 1) / SCHUNK;

    // ---- workspace budget check ----
    auto rup = [](size_t b) { return (b + 255) & ~(size_t)255; };
    size_t need = 0;
    need += rup((size_t)N * 4) * 4;                 // cnt_node,row_start,cursor,dinv
    need += rup((size_t)N * 4);                     // T3
    need += rup((size_t)nb * 4) * 2;                // bsum,bstart
    need += rup((size_t)B * 4) * 2;                 // gcnt,gstart
    need += rup((size_t)E * 4) * 2;                 // csr_src,csr_w
    need += rup((size_t)N * 128 * 4);               // T
    need += rup((size_t)N * FSTR * 4);              // feat (padded stride)
    need += rup((size_t)B * KTOP * 4);              // sel
    need += rup((size_t)B * C1 * KTOP * 4);         // h1
    if (need > ws_size) {
        hipMemsetAsync(d_out, 0, (size_t)out_size * 4, stream);
        return;
    }

    // workspace carve
    char* p = (char*)d_ws;
    auto alloc = [&](size_t bytes) { void* r = (void*)p; p += (bytes + 255) & ~(size_t)255; return r; };
    int*   cnt_node  = (int*)alloc((size_t)N * 4);
    int*   row_start = (int*)alloc((size_t)N * 4);
    int*   cursor    = (int*)alloc((size_t)N * 4);
    float* dinv      = (float*)alloc((size_t)N * 4);
    float* T3        = (float*)alloc((size_t)N * 4);
    int*   bsum      = (int*)alloc((size_t)nb * 4);
    int*   bstart    = (int*)alloc((size_t)nb * 4);
    int*   gcnt      = (int*)alloc((size_t)B * 4);
    int*   gstart    = (int*)alloc((size_t)B * 4);
    int*   csr_src   = (int*)alloc((size_t)E * 4);
    float* csr_w     = (float*)alloc((size_t)E * 4);
    float* T         = (float*)alloc((size_t)N * 128 * 4);
    float* feat      = (float*)alloc((size_t)N * FSTR * 4);
    int*   sel       = (int*)alloc((size_t)B * KTOP * 4);
    float* h1        = (float*)alloc((size_t)B * C1 * KTOP * 4);

    hipMemsetAsync(cnt_node, 0, (size_t)N * 4, stream);
    hipMemsetAsync(gcnt,     0, (size_t)B * 4, stream);

    hist_kernel<<<(E + 255) / 256, 256, 0, stream>>>(dst, E, N, cnt_node);
    hist_kernel<<<(N + 255) / 256, 256, 0, stream>>>(batch, N, B, gcnt);

    // hierarchical exclusive scan over node degrees
    chunksum_kernel<<<nb, 256, 0, stream>>>(cnt_node, N, bsum);
    scan_excl_kernel<<<1, 1024, 0, stream>>>(bsum, nb, bstart, nullptr, nullptr);
    scan_apply_kernel<<<nb, 256, 0, stream>>>(cnt_node, N, bstart, row_start, cursor, dinv);
    // per-graph counts: B=512 -> single chunk, keep simple scan
    scan_excl_kernel<<<1, 1024, 0, stream>>>(gcnt, B, gstart, nullptr, nullptr);

    csr_fill_kernel<<<(E + 255) / 256, 256, 0, stream>>>(src, dst, E, N, cursor, dinv, csr_src, csr_w);

    dim3 ggrid((N + 63) / 64, 2);
    const int agg_grid = (N + AGG_NPB - 1) / AGG_NPB;
    // layer 0: x(F=128, lda=128) -> feat cols [0,128)
    gemm_nk128<<<ggrid, 256, 0, stream>>>(x, F_IN, Wg0, T, N);
    gcn_agg128<<<agg_grid, 256, 0, stream>>>(T, csr_src, csr_w, row_start, cnt_node, dinv, bg0, feat, 0, N, nullptr, nullptr);
    // layer 1: feat cols [0,128) (lda=FSTR) -> [128,256)
    gemm_nk128<<<ggrid, 256, 0, stream>>>(feat, FSTR, Wg1, T, N);
    gcn_agg128<<<agg_grid, 256, 0, stream>>>(T, csr_src, csr_w, row_start, cnt_node, dinv, bg1, feat, 1, N, nullptr, nullptr);
    // layer 2: feat cols [128,256) -> [256,384), fused with layer-3 GEMV -> T3
    gemm_nk128<<<ggrid, 256, 0, stream>>>(feat + 128, FSTR, Wg2, T, N);
    gcn_agg128<<<agg_grid, 256, 0, stream>>>(T, csr_src, csr_w, row_start, cnt_node, dinv, bg2, feat, 2, N, Wg3, T3);
    // layer 3 aggregation (1 channel)
    gcn_agg1<<<(N + 255) / 256, 256, 0, stream>>>(T3, csr_src, csr_w, row_start, cnt_node, dinv, bg3, feat, N);

    sortpool_kernel<<<B, 256, 0, stream>>>(feat, gcnt, gstart, sel);
    conv1_kernel<<<(B * KTOP + C1SLOTS - 1) / C1SLOTS, 256, 0, stream>>>(feat, sel, W1, b1, h1, B * KTOP);
    head_kernel<<<B, 256, 0, stream>>>(h1, W2, b2, Wm1, bm1, Wm2, bm2, out);
}

// Round 15
// 1122.633 us; speedup vs baseline: 1.8022x; 1.0588x over previous
//
#include <hip/hip_runtime.h>
#include <hip/hip_bf16.h>
#include <cfloat>

// Problem constants (match reference)
#define F_IN   128
#define H_DIM  128
#define D_TOT  385          // H*L + 1 (logical feature dim)
#define FSTR   388          // padded feat row stride (16B-aligned float4 rows)
#define KTOP   100
#define C1     16
#define C2     32
#define KW2    5
#define POOLW  (KTOP/2)             // 50
#define CONV2W (POOLW - KW2 + 1)    // 46
#define DENSE  (C2*CONV2W)          // 1472
#define MLPH   128
#define SORT_CAP 2048
#define D_PAD  388                  // conv1 W1 LDS row pad
#define CV3_SLOTS 64                // slots per conv1 block (16 groups x 4)
#define SCHUNK 1024                 // scan chunk
#define AGG_NPB 8                   // nodes per aggregation block

// ---------------- histogram (int32 keys, clamped) ----------------
__global__ void hist_kernel(const int* __restrict__ keys, int n, int nbins, int* __restrict__ cnt) {
    int i = blockIdx.x * blockDim.x + threadIdx.x;
    if (i < n) {
        int k = keys[i];
        k = (k < 0) ? 0 : (k >= nbins ? nbins - 1 : k);
        atomicAdd(&cnt[k], 1);
    }
}

// ---------------- single-block exclusive scan (small n / chunk sums) ----------------
__global__ void scan_excl_kernel(const int* __restrict__ cnt, int n,
                                 int* __restrict__ start, int* __restrict__ cursor,
                                 float* __restrict__ dinv) {
    __shared__ int s[1024];
    __shared__ int carry_s;
    int tid = threadIdx.x;
    if (tid == 0) carry_s = 0;
    __syncthreads();
    for (int base = 0; base < n; base += 1024) {
        int i = base + tid;
        int v = (i < n) ? cnt[i] : 0;
        s[tid] = v;
        __syncthreads();
        for (int off = 1; off < 1024; off <<= 1) {
            int t = (tid >= off) ? s[tid - off] : 0;
            __syncthreads();
            s[tid] += t;
            __syncthreads();
        }
        int excl = s[tid] - v;
        int carry = carry_s;
        if (i < n) {
            start[i] = carry + excl;
            if (cursor) cursor[i] = carry + excl;
            if (dinv)   dinv[i]   = rsqrtf((float)v + 1.0f);
        }
        __syncthreads();
        if (tid == 0) carry_s += s[1023];
        __syncthreads();
    }
}

// ---------------- hierarchical scan, phase 1: per-chunk sums ----------------
__global__ __launch_bounds__(256) void chunksum_kernel(const int* __restrict__ cnt, int n,
                                                       int* __restrict__ bsum) {
    __shared__ int red[256];
    int blk = blockIdx.x, tid = threadIdx.x;
    int base = blk * SCHUNK;
    int s = 0;
    for (int idx = tid; idx < SCHUNK; idx += 256) {
        int i = base + idx;
        s += (i < n) ? cnt[i] : 0;
    }
    red[tid] = s; __syncthreads();
    for (int off = 128; off > 0; off >>= 1) {
        if (tid < off) red[tid] += red[tid + off];
        __syncthreads();
    }
    if (tid == 0) bsum[blk] = red[0];
}

// ---------------- hierarchical scan, phase 3: apply ----------------
__global__ __launch_bounds__(256) void scan_apply_kernel(const int* __restrict__ cnt, int n,
                                                         const int* __restrict__ bstart,
                                                         int* __restrict__ start,
                                                         int* __restrict__ cursor,
                                                         float* __restrict__ dinv) {
    __shared__ int tsum[256];
    int blk = blockIdx.x, tid = threadIdx.x;
    int base = blk * SCHUNK + tid * 4;
    int v[4];
    #pragma unroll
    for (int k = 0; k < 4; k++) { int i = base + k; v[k] = (i < n) ? cnt[i] : 0; }
    int loc = v[0] + v[1] + v[2] + v[3];
    tsum[tid] = loc; __syncthreads();
    int x = loc;
    for (int off = 1; off < 256; off <<= 1) {
        int t = (tid >= off) ? tsum[tid - off] : 0;
        __syncthreads();
        x += t; tsum[tid] = x;
        __syncthreads();
    }
    int run = x - loc + bstart[blk];
    #pragma unroll
    for (int k = 0; k < 4; k++) {
        int i = base + k;
        if (i < n) {
            start[i]  = run;
            cursor[i] = run;
            dinv[i]   = rsqrtf((float)v[k] + 1.0f);
        }
        run += v[k];
    }
}

// ---------------- CSR fill (edges bucketed by dst, clamped) ----------------
__global__ void csr_fill_kernel(const int* __restrict__ src, const int* __restrict__ dst, int e, int n,
                                int* __restrict__ cursor, const float* __restrict__ dinv,
                                int* __restrict__ csr_src, float* __restrict__ csr_w) {
    int i = blockIdx.x * blockDim.x + threadIdx.x;
    if (i < e) {
        int s = src[i], d = dst[i];
        s = (s < 0) ? 0 : (s >= n ? n - 1 : s);
        d = (d < 0) ? 0 : (d >= n ? n - 1 : d);
        int pos = atomicAdd(&cursor[d], 1);
        csr_src[pos] = s;
        csr_w[pos]   = dinv[s] * dinv[d];
    }
}

// ---------------- fp32 GEMM v2: T[n,128] = A[n,:](lda) @ W[128,128] ----------------
__global__ __launch_bounds__(256) void gemm_nk128(const float* __restrict__ A, int lda,
                                                  const float* __restrict__ W,
                                                  float* __restrict__ T, int n) {
    __shared__ float Wl[128 * 64];
    int tid = threadIdx.x;
    int brow = blockIdx.x * 64;
    int chalf = blockIdx.y;          // 0/1 -> cols [0,64) or [64,128)

    for (int kk = tid >> 4; kk < 128; kk += 16) {
        int c4 = tid & 15;
        float4 w = *(const float4*)&W[kk * 128 + chalf * 64 + c4 * 4];
        *(float4*)&Wl[kk * 64 + c4 * 4] = w;
    }
    __syncthreads();

    int tr = tid >> 4, tc = tid & 15;
    int r0 = brow + tr * 4;
    int c0 = tc * 4;
    // clamp row pointers (values unused when r >= n; stores guarded)
    const float* pa0 = A + (size_t)((r0 + 0 < n) ? r0 + 0 : n - 1) * lda;
    const float* pa1 = A + (size_t)((r0 + 1 < n) ? r0 + 1 : n - 1) * lda;
    const float* pa2 = A + (size_t)((r0 + 2 < n) ? r0 + 2 : n - 1) * lda;
    const float* pa3 = A + (size_t)((r0 + 3 < n) ? r0 + 3 : n - 1) * lda;

    float acc[4][4] = {};
    #pragma unroll 8
    for (int kk = 0; kk < 128; kk += 4) {
        float4 a0 = *(const float4*)&pa0[kk];
        float4 a1 = *(const float4*)&pa1[kk];
        float4 a2 = *(const float4*)&pa2[kk];
        float4 a3 = *(const float4*)&pa3[kk];
        float4 w0 = *(const float4*)&Wl[(kk + 0) * 64 + c0];
        float4 w1 = *(const float4*)&Wl[(kk + 1) * 64 + c0];
        float4 w2 = *(const float4*)&Wl[(kk + 2) * 64 + c0];
        float4 w3 = *(const float4*)&Wl[(kk + 3) * 64 + c0];
        // k-sequential accumulation per output (bit-identical to v1)
        #define ROWFMA(i, ai)                                              \
            acc[i][0] += ai.x * w0.x; acc[i][1] += ai.x * w0.y;            \
            acc[i][2] += ai.x * w0.z; acc[i][3] += ai.x * w0.w;            \
            acc[i][0] += ai.y * w1.x; acc[i][1] += ai.y * w1.y;            \
            acc[i][2] += ai.y * w1.z; acc[i][3] += ai.y * w1.w;            \
            acc[i][0] += ai.z * w2.x; acc[i][1] += ai.z * w2.y;            \
            acc[i][2] += ai.z * w2.z; acc[i][3] += ai.z * w2.w;            \
            acc[i][0] += ai.w * w3.x; acc[i][1] += ai.w * w3.y;            \
            acc[i][2] += ai.w * w3.z; acc[i][3] += ai.w * w3.w;
        ROWFMA(0, a0) ROWFMA(1, a1) ROWFMA(2, a2) ROWFMA(3, a3)
        #undef ROWFMA
    }
    for (int i = 0; i < 4; i++) {
        int r = brow + tr * 4 + i;
        if (r < n) {
            float4 o = make_float4(acc[i][0], acc[i][1], acc[i][2], acc[i][3]);
            *(float4*)&T[(size_t)r * 128 + chalf * 64 + c0] = o;
        }
    }
}

// ---------------- GCN aggregation (128-channel), pull-based ----------------
// 8 nodes per 256-thread block; 32 lanes per node, float4 per lane.
__global__ __launch_bounds__(256) void gcn_agg128(const float* __restrict__ T,
                                                  const int* __restrict__ csr_src,
                                                  const float* __restrict__ csr_w,
                                                  const int* __restrict__ row_start,
                                                  const int* __restrict__ cnt,
                                                  const float* __restrict__ dinv,
                                                  const float* __restrict__ bias,
                                                  float* __restrict__ feat, int layer, int n,
                                                  const float* __restrict__ Wg3,
                                                  float* __restrict__ T3) {
    int g    = threadIdx.x >> 5;          // node group 0..7
    int lane = threadIdx.x & 31;
    int i = blockIdx.x * AGG_NPB + g;
    if (i >= n) return;                   // no barriers below -> safe divergence
    int c4 = lane << 2;                   // channel base (16B aligned in T)
    float di = dinv[i];
    float s2 = di * di;
    float4 self = *(const float4*)&T[(size_t)i * 128 + c4];
    float4 acc = make_float4(self.x * s2, self.y * s2, self.z * s2, self.w * s2);
    int rs = row_start[i], ce = cnt[i];
    for (int e = 0; e < ce; e++) {
        int s  = csr_src[rs + e];
        float w = csr_w[rs + e];
        float4 v = *(const float4*)&T[(size_t)s * 128 + c4];
        acc.x += v.x * w; acc.y += v.y * w; acc.z += v.z * w; acc.w += v.w * w;
    }
    float4 bb = *(const float4*)&bias[c4];
    float4 vt = make_float4(tanhf(acc.x + bb.x), tanhf(acc.y + bb.y),
                            tanhf(acc.z + bb.z), tanhf(acc.w + bb.w));
    // FSTR=388 -> 16B-aligned float4 store
    *(float4*)&feat[(size_t)i * FSTR + layer * 128 + c4] = vt;
    if (T3 != nullptr) {                  // uniform branch (layer 2 only)
        float4 wg = *(const float4*)&Wg3[c4];
        float4 p = make_float4(vt.x * wg.x, vt.y * wg.y, vt.z * wg.z, vt.w * wg.w);
        #pragma unroll
        for (int off = 16; off > 0; off >>= 1) {
            p.x += __shfl_down(p.x, off, 32);
            p.y += __shfl_down(p.y, off, 32);
            p.z += __shfl_down(p.z, off, 32);
            p.w += __shfl_down(p.w, off, 32);
        }
        if (lane == 0) T3[i] = (p.x + p.z) + (p.y + p.w);
    }
}

// ---------------- layer 3 aggregation (1 channel) ----------------
__global__ void gcn_agg1(const float* __restrict__ T3,
                         const int* __restrict__ csr_src, const float* __restrict__ csr_w,
                         const int* __restrict__ row_start, const int* __restrict__ cnt,
                         const float* __restrict__ dinv, const float* __restrict__ bg3,
                         float* __restrict__ feat, int n) {
    int i = blockIdx.x * blockDim.x + threadIdx.x;
    if (i >= n) return;
    float di = dinv[i];
    float acc = T3[i] * di * di;
    int rs = row_start[i], ce = cnt[i];
    for (int e = 0; e < ce; e++) acc += T3[csr_src[rs + e]] * csr_w[rs + e];
    feat[(size_t)i * FSTR + (D_TOT - 1)] = tanhf(acc + bg3[0]);
}

// ---------------- sort-pool: per-graph bitonic sort ----------------
// EXACT reference semantics: stable ascending argsort of fp32 key
//   key = 4.0f*(float)b - feat[:,-1]
__global__ __launch_bounds__(256) void sortpool_kernel(const float* __restrict__ feat,
                                                       const int* __restrict__ gcnt,
                                                       const int* __restrict__ gstart,
                                                       int* __restrict__ sel) {
    int b = blockIdx.x, tid = threadIdx.x;
    __shared__ float sv[SORT_CAP];
    __shared__ int   si[SORT_CAP];
    int cnt = gcnt[b];
    if (cnt > SORT_CAP) cnt = SORT_CAP;
    int start = gstart[b];
    if (cnt == 0) {
        for (int j = tid; j < KTOP; j += 256) sel[b * KTOP + j] = -1;
        return;
    }
    float bb = 4.0f * (float)b;    // exact in fp32
    int P = 1; while (P < cnt) P <<= 1;
    for (int j = tid; j < P; j += 256) {
        if (j < cnt) {
            float v = feat[(size_t)(start + j) * FSTR + (D_TOT - 1)];
            sv[j] = bb - v;        // single fp32 rounding, matches reference
            si[j] = j;
        } else { sv[j] = FLT_MAX; si[j] = j; }
    }
    __syncthreads();
    for (int ksz = 2; ksz <= P; ksz <<= 1) {
        for (int jj = ksz >> 1; jj > 0; jj >>= 1) {
            for (int t = tid; t < P; t += 256) {
                int l = t ^ jj;
                if (l > t) {
                    float va = sv[t], vb = sv[l];
                    int   ia = si[t], ib = si[l];
                    bool aFirst = (va < vb) || (va == vb && ia < ib);
                    bool up = ((t & ksz) == 0);
                    if (up ? !aFirst : aFirst) {
                        sv[t] = vb; sv[l] = va; si[t] = ib; si[l] = ia;
                    }
                }
            }
            __syncthreads();
        }
    }
    for (int j = tid; j < KTOP; j += 256)
        sel[b * KTOP + j] = (j < cnt) ? (start + si[j]) : -1;
}

// ---------------- conv1 v3: W1-only LDS + direct global float4 row reads ----------------
// v2 (141 us): 73 KiB LDS (W1 + 32 staged rows) -> 2 blocks/CU, 17.6% occupancy,
// latency-bound (VALUBusy 17.7%), 72 scalar staging iters/block.
// v3: only W1 in LDS (24832 B -> ~6 blocks/CU by LDS). feat rows are FSTR-padded
// (row base 16B-aligned) -> read directly from global as broadcast float4, same
// pattern that fixed gemm v2. 16 row-groups x 16 output lanes; each thread does
// 4 slots x 1 output: per 4k-step 4 global b128 + 1 LDS b128 + 16 FMA.
// Per-output t-order identical to v2 -> identical rounding (absmax stays 0).
__global__ __launch_bounds__(256) void conv1_kernel(const float* __restrict__ feat,
                                                    const int* __restrict__ sel,
                                                    const float* __restrict__ W1,
                                                    const float* __restrict__ b1,
                                                    float* __restrict__ h1, int nslots) {
    __shared__ float W1l[C1 * D_PAD];        // 24832 B
    int tid = threadIdx.x;
    for (int idx = tid; idx < C1 * D_TOT; idx += 256) {
        int o = idx / D_TOT, t = idx - o * D_TOT;
        W1l[o * D_PAD + t] = W1[idx];
    }
    __syncthreads();

    int tr = tid >> 4, o = tid & 15;
    int base = blockIdx.x * CV3_SLOTS + tr * 4;
    const float* wr = &W1l[o * D_PAD];

    int   rown[4];
    float mask[4];
    #pragma unroll
    for (int i = 0; i < 4; i++) {
        int slot = base + i;
        int row = (slot < nslots) ? sel[slot] : -1;
        mask[i] = (row >= 0) ? 1.0f : 0.0f;
        rown[i] = (row >= 0) ? row : 0;
    }
    const float* p0 = feat + (size_t)rown[0] * FSTR;
    const float* p1 = feat + (size_t)rown[1] * FSTR;
    const float* p2 = feat + (size_t)rown[2] * FSTR;
    const float* p3 = feat + (size_t)rown[3] * FSTR;

    float a0 = 0.f, a1 = 0.f, a2 = 0.f, a3 = 0.f;
    #pragma unroll 8
    for (int t = 0; t < 384; t += 4) {
        float4 w  = *(const float4*)&wr[t];
        float4 x0 = *(const float4*)&p0[t];
        float4 x1 = *(const float4*)&p1[t];
        float4 x2 = *(const float4*)&p2[t];
        float4 x3 = *(const float4*)&p3[t];
        a0 += x0.x * w.x + x0.y * w.y + x0.z * w.z + x0.w * w.w;
        a1 += x1.x * w.x + x1.y * w.y + x1.z * w.z + x1.w * w.w;
        a2 += x2.x * w.x + x2.y * w.y + x2.z * w.z + x2.w * w.w;
        a3 += x3.x * w.x + x3.y * w.y + x3.z * w.z + x3.w * w.w;
    }
    float wl = wr[384];
    a0 += p0[384] * wl; a1 += p1[384] * wl; a2 += p2[384] * wl; a3 += p3[384] * wl;

    float bo = b1[o];
    float av[4] = {a0, a1, a2, a3};
    #pragma unroll
    for (int i = 0; i < 4; i++) {
        int slot = base + i;
        if (slot < nslots) {
            int b = slot / KTOP, j = slot - b * KTOP;
            h1[((size_t)b * C1 + o) * KTOP + j] = fmaxf(av[i] * mask[i] + bo, 0.f);
        }
    }
}

// ---------------- head: maxpool + conv2 + MLP, one block per graph ----------------
__global__ __launch_bounds__(256) void head_kernel(const float* __restrict__ h1,
                                                   const float* __restrict__ W2, const float* __restrict__ b2,
                                                   const float* __restrict__ Wm1, const float* __restrict__ bm1,
                                                   const float* __restrict__ Wm2, const float* __restrict__ bm2,
                                                   float* __restrict__ out) {
    int b = blockIdx.x, tid = threadIdx.x;
    __shared__ float pool[C1 * POOLW];   // 800
    __shared__ float flat[DENSE];        // 1472
    __shared__ float hid[MLPH];          // 128
    __shared__ float red[256];

    for (int p = tid; p < C1 * POOLW; p += 256) {
        int i = p / POOLW, t = p % POOLW;
        float v0 = h1[((size_t)b * C1 + i) * KTOP + 2 * t];
        float v1 = h1[((size_t)b * C1 + i) * KTOP + 2 * t + 1];
        pool[i * POOLW + t] = fmaxf(v0, v1);
    }
    __syncthreads();
    for (int q = tid; q < DENSE; q += 256) {
        int o = q / CONV2W, t = q % CONV2W;
        float acc = b2[o];
        #pragma unroll
        for (int i = 0; i < C1; i++) {
            #pragma unroll
            for (int ks = 0; ks < KW2; ks++)
                acc += pool[i * POOLW + t + ks] * W2[(o * C1 + i) * KW2 + ks];
        }
        flat[o * CONV2W + t] = fmaxf(acc, 0.f);
    }
    __syncthreads();
    {
        int h = tid & 127, part = tid >> 7;     // 2 partials per output
        float acc = 0.f;
        for (int t = part * (DENSE / 2); t < (part + 1) * (DENSE / 2); t++)
            acc += flat[t] * Wm1[(size_t)t * MLPH + h];
        red[tid] = acc;
    }
    __syncthreads();
    if (tid < 128) hid[tid] = fmaxf(red[tid] + red[tid + 128] + bm1[tid], 0.f);
    __syncthreads();
    if (tid < 64) {
        float p = hid[tid] * Wm2[tid] + hid[tid + 64] * Wm2[tid + 64];
        #pragma unroll
        for (int off = 32; off > 0; off >>= 1) p += __shfl_down(p, off, 64);
        if (tid == 0) out[b] = p + bm2[0];
    }
}

// ================= launch =================
extern "C" void kernel_launch(void* const* d_in, const int* in_sizes, int n_in,
                              void* d_out, int out_size, void* d_ws, size_t ws_size,
                              hipStream_t stream) {
    const float* x     = (const float*)d_in[0];
    const int*   ei    = (const int*)d_in[1];
    const int*   batch = (const int*)d_in[2];
    const float* Wg0 = (const float*)d_in[4],  *bg0 = (const float*)d_in[5];
    const float* Wg1 = (const float*)d_in[6],  *bg1 = (const float*)d_in[7];
    const float* Wg2 = (const float*)d_in[8],  *bg2 = (const float*)d_in[9];
    const float* Wg3 = (const float*)d_in[10], *bg3 = (const float*)d_in[11];
    const float* W1  = (const float*)d_in[12], *b1  = (const float*)d_in[13];
    const float* W2  = (const float*)d_in[14], *b2  = (const float*)d_in[15];
    const float* Wm1 = (const float*)d_in[16], *bm1 = (const float*)d_in[17];
    const float* Wm2 = (const float*)d_in[18], *bm2 = (const float*)d_in[19];
    float* out = (float*)d_out;

    const int N = in_sizes[2];        // batch has N elements
    const int E = in_sizes[1] / 2;
    const int B = out_size;           // 512
    const int* src = ei;
    const int* dst = ei + E;
    const int nb = (N + SCHUNK - 1) / SCHUNK;

    // ---- workspace budget check ----
    auto rup = [](size_t b) { return (b + 255) & ~(size_t)255; };
    size_t need = 0;
    need += rup((size_t)N * 4) * 4;                 // cnt_node,row_start,cursor,dinv
    need += rup((size_t)N * 4);                     // T3
    need += rup((size_t)nb * 4) * 2;                // bsum,bstart
    need += rup((size_t)B * 4) * 2;                 // gcnt,gstart
    need += rup((size_t)E * 4) * 2;                 // csr_src,csr_w
    need += rup((size_t)N * 128 * 4);               // T
    need += rup((size_t)N * FSTR * 4);              // feat (padded stride)
    need += rup((size_t)B * KTOP * 4);              // sel
    need += rup((size_t)B * C1 * KTOP * 4);         // h1
    if (need > ws_size) {
        hipMemsetAsync(d_out, 0, (size_t)out_size * 4, stream);
        return;
    }

    // workspace carve
    char* p = (char*)d_ws;
    auto alloc = [&](size_t bytes) { void* r = (void*)p; p += (bytes + 255) & ~(size_t)255; return r; };
    int*   cnt_node  = (int*)alloc((size_t)N * 4);
    int*   row_start = (int*)alloc((size_t)N * 4);
    int*   cursor    = (int*)alloc((size_t)N * 4);
    float* dinv      = (float*)alloc((size_t)N * 4);
    float* T3        = (float*)alloc((size_t)N * 4);
    int*   bsum      = (int*)alloc((size_t)nb * 4);
    int*   bstart    = (int*)alloc((size_t)nb * 4);
    int*   gcnt      = (int*)alloc((size_t)B * 4);
    int*   gstart    = (int*)alloc((size_t)B * 4);
    int*   csr_src   = (int*)alloc((size_t)E * 4);
    float* csr_w     = (float*)alloc((size_t)E * 4);
    float* T         = (float*)alloc((size_t)N * 128 * 4);
    float* feat      = (float*)alloc((size_t)N * FSTR * 4);
    int*   sel       = (int*)alloc((size_t)B * KTOP * 4);
    float* h1        = (float*)alloc((size_t)B * C1 * KTOP * 4);

    hipMemsetAsync(cnt_node, 0, (size_t)N * 4, stream);
    hipMemsetAsync(gcnt,     0, (size_t)B * 4, stream);

    hist_kernel<<<(E + 255) / 256, 256, 0, stream>>>(dst, E, N, cnt_node);
    hist_kernel<<<(N + 255) / 256, 256, 0, stream>>>(batch, N, B, gcnt);

    // hierarchical exclusive scan over node degrees
    chunksum_kernel<<<nb, 256, 0, stream>>>(cnt_node, N, bsum);
    scan_excl_kernel<<<1, 1024, 0, stream>>>(bsum, nb, bstart, nullptr, nullptr);
    scan_apply_kernel<<<nb, 256, 0, stream>>>(cnt_node, N, bstart, row_start, cursor, dinv);
    // per-graph counts: B=512 -> single chunk, keep simple scan
    scan_excl_kernel<<<1, 1024, 0, stream>>>(gcnt, B, gstart, nullptr, nullptr);

    csr_fill_kernel<<<(E + 255) / 256, 256, 0, stream>>>(src, dst, E, N, cursor, dinv, csr_src, csr_w);

    dim3 ggrid((N + 63) / 64, 2);
    const int agg_grid = (N + AGG_NPB - 1) / AGG_NPB;
    // layer 0: x(F=128, lda=128) -> feat cols [0,128)
    gemm_nk128<<<ggrid, 256, 0, stream>>>(x, F_IN, Wg0, T, N);
    gcn_agg128<<<agg_grid, 256, 0, stream>>>(T, csr_src, csr_w, row_start, cnt_node, dinv, bg0, feat, 0, N, nullptr, nullptr);
    // layer 1: feat cols [0,128) (lda=FSTR) -> [128,256)
    gemm_nk128<<<ggrid, 256, 0, stream>>>(feat, FSTR, Wg1, T, N);
    gcn_agg128<<<agg_grid, 256, 0, stream>>>(T, csr_src, csr_w, row_start, cnt_node, dinv, bg1, feat, 1, N, nullptr, nullptr);
    // layer 2: feat cols [128,256) -> [256,384), fused with layer-3 GEMV -> T3
    gemm_nk128<<<ggrid, 256, 0, stream>>>(feat + 128, FSTR, Wg2, T, N);
    gcn_agg128<<<agg_grid, 256, 0, stream>>>(T, csr_src, csr_w, row_start, cnt_node, dinv, bg2, feat, 2, N, Wg3, T3);
    // layer 3 aggregation (1 channel)
    gcn_agg1<<<(N + 255) / 256, 256, 0, stream>>>(T3, csr_src, csr_w, row_start, cnt_node, dinv, bg3, feat, N);

    sortpool_kernel<<<B, 256, 0, stream>>>(feat, gcnt, gstart, sel);
    conv1_kernel<<<(B * KTOP + CV3_SLOTS - 1) / CV3_SLOTS, 256, 0, stream>>>(feat, sel, W1, b1, h1, B * KTOP);
    head_kernel<<<B, 256, 0, stream>>>(h1, W2, b2, Wm1, bm1, Wm2, bm2, out);
}